// Round 3
// baseline (962.270 us; speedup 1.0000x reference)
//
#include <hip/hip_runtime.h>

#define NS_ 100000
#define NW_ 400000
#define NE_ 500000
#define EPB 2048   // elements per scan block

__device__ __forceinline__ float lrelu02(float x) { return x > 0.f ? x : 0.2f * x; }
__device__ __forceinline__ float bf2f(unsigned short u) {
    return __uint_as_float(((unsigned)u) << 16);
}
__device__ __forceinline__ unsigned short f2bf(float f) {
    unsigned u = __float_as_uint(f);
    u += 0x7FFFu + ((u >> 16) & 1u);           // round-to-nearest-even
    return (unsigned short)(u >> 16);
}

// ---------------------------------------------------------------------------
// xs(bf16) = x_sites @ W_sw ([NS,256]) and al_s[n,h] = xs[n,h,:]·att_src[h,:]
// ---------------------------------------------------------------------------
__global__ void __launch_bounds__(256)
k_sites_pre(const float* __restrict__ x_sites, const float* __restrict__ W_sw,
            const float* __restrict__ att_src, unsigned short* __restrict__ xs,
            float* __restrict__ al_s)
{
    __shared__ float xlds[32][68];
    const int tid = threadIdx.x;
    float w[64];
#pragma unroll
    for (int d = 0; d < 64; ++d) w[d] = W_sw[d * 256 + tid];
    const float att = att_src[tid];
    const int base = blockIdx.x * 32;
    for (int i = tid; i < 32 * 64; i += 256) {
        int s = i >> 6, d = i & 63;
        xlds[s][d] = x_sites[(size_t)(base + s) * 64 + d];
    }
    __syncthreads();
    const int head = tid >> 6, lane = tid & 63;
    for (int s = 0; s < 32; ++s) {
        const float4* xr = (const float4*)(&xlds[s][0]);
        float acc = 0.f;
#pragma unroll
        for (int d4 = 0; d4 < 16; ++d4) {
            float4 xv = xr[d4];
            acc += xv.x * w[4 * d4] + xv.y * w[4 * d4 + 1] + xv.z * w[4 * d4 + 2] + xv.w * w[4 * d4 + 3];
        }
        xs[(size_t)(base + s) * 256 + tid] = f2bf(acc);
        float p = acc * att;
#pragma unroll
        for (int off = 32; off > 0; off >>= 1) p += __shfl_down(p, off, 64);
        if (lane == 0) al_s[(size_t)(base + s) * 4 + head] = p;
    }
}

// vd[d*4+h] = sum_c W_sw[d, h*64+c] * att_dst[h,c]   (single block)
__global__ void __launch_bounds__(256)
k_vd(const float* __restrict__ W_sw, const float* __restrict__ att_dst,
     float* __restrict__ vd)
{
    const int tid = threadIdx.x;
    const int d = tid >> 2, h = tid & 3;
    const float4* wp = (const float4*)(W_sw + d * 256 + h * 64);
    const float4* ap = (const float4*)(att_dst + h * 64);
    float acc = 0.f;
#pragma unroll
    for (int c = 0; c < 16; ++c) {
        float4 wv = wp[c]; float4 av = ap[c];
        acc += wv.x * av.x + wv.y * av.y + wv.z * av.z + wv.w * av.w;
    }
    vd[d * 4 + h] = acc;
}

// ---------------------------------------------------------------------------
// CSR build: histogram -> 3-phase scan -> scatter (both relations via y-dim)
// ---------------------------------------------------------------------------
__global__ void __launch_bounds__(256)
k_hist2(const int* __restrict__ d1, int* __restrict__ h1,
        const int* __restrict__ d2, int* __restrict__ h2)
{
    int e = blockIdx.x * 256 + threadIdx.x;
    if (e >= NE_) return;
    if (blockIdx.y == 0) atomicAdd(&h1[d1[e]], 1);
    else                 atomicAdd(&h2[d2[e]], 1);
}

__global__ void __launch_bounds__(256)
k_scan1(const int* __restrict__ hist, int n, int* __restrict__ bsum)
{
    __shared__ int red[256];
    const int tid = threadIdx.x;
    int base = blockIdx.x * EPB + tid * 8;
    int s = 0;
#pragma unroll
    for (int i = 0; i < 8; ++i) { int idx = base + i; if (idx < n) s += hist[idx]; }
    red[tid] = s;
    __syncthreads();
    for (int off = 128; off > 0; off >>= 1) {
        if (tid < off) red[tid] += red[tid + off];
        __syncthreads();
    }
    if (tid == 0) bsum[blockIdx.x] = red[0];
}

__global__ void __launch_bounds__(256)
k_scan2(int* __restrict__ bsum, int nb)
{
    __shared__ int sh[256];
    const int tid = threadIdx.x;
    sh[tid] = (tid < nb) ? bsum[tid] : 0;
    __syncthreads();
    for (int off = 1; off < 256; off <<= 1) {
        int u = (tid >= off) ? sh[tid - off] : 0;
        __syncthreads();
        sh[tid] += u;
        __syncthreads();
    }
    if (tid < nb) bsum[tid] = (tid == 0) ? 0 : sh[tid - 1];
}

__global__ void __launch_bounds__(256)
k_scan3(const int* __restrict__ hist, int n, const int* __restrict__ bsum,
        int* __restrict__ rowptr, int* __restrict__ cursor, int total)
{
    __shared__ int tsum[256];
    const int tid = threadIdx.x;
    int base = blockIdx.x * EPB + tid * 8;
    int v[8]; int s = 0;
#pragma unroll
    for (int i = 0; i < 8; ++i) {
        int idx = base + i;
        v[i] = (idx < n) ? hist[idx] : 0;
        s += v[i];
    }
    tsum[tid] = s;
    __syncthreads();
    for (int off = 1; off < 256; off <<= 1) {
        int u = (tid >= off) ? tsum[tid - off] : 0;
        __syncthreads();
        tsum[tid] += u;
        __syncthreads();
    }
    int texcl = tsum[tid] - s;
    int run = bsum[blockIdx.x] + texcl;
#pragma unroll
    for (int i = 0; i < 8; ++i) {
        int idx = base + i;
        if (idx < n) { rowptr[idx] = run; cursor[idx] = run; run += v[i]; }
    }
    if (blockIdx.x == 0 && tid == 0) rowptr[n] = total;
}

__global__ void __launch_bounds__(256)
k_scatter2(const int* __restrict__ s1, const int* __restrict__ d1,
           int* __restrict__ c1, int* __restrict__ o1,
           const int* __restrict__ s2, const int* __restrict__ d2,
           int* __restrict__ c2, int* __restrict__ o2)
{
    int e = blockIdx.x * 256 + threadIdx.x;
    if (e >= NE_) return;
    if (blockIdx.y == 0) { int p = atomicAdd(&c1[d1[e]], 1); o1[p] = s1[e]; }
    else                 { int p = atomicAdd(&c2[d2[e]], 1); o2[p] = s2[e]; }
}

// ---------------------------------------------------------------------------
// Fused GAT gather + self-loop SAGE + relu + Wg head for wells.
// Tile = 64 wells/block. GAT phase: 16 lanes/well. Dense phase: wave/well,
// lane = channel, weight column in 64 VGPRs, x via broadcast LDS b128 reads.
// ---------------------------------------------------------------------------
__global__ void __launch_bounds__(256)
k_gat_wells(const float* __restrict__ x_wells, const float* __restrict__ vd,
            const int* __restrict__ rowptr, const int* __restrict__ csr_src,
            const float* __restrict__ al_s, const unsigned short* __restrict__ xs,
            const float* __restrict__ Wl_ww, const float* __restrict__ Wr_ww,
            const float* __restrict__ b_sw, const float* __restrict__ bl_ww,
            const float* __restrict__ Wg, const float* __restrict__ bg,
            float* __restrict__ out)
{
    __shared__ float xw[64][68];
    __shared__ float tl[64][68];
    __shared__ float vdl[256];
    __shared__ float biasl[64], wgl[64];
    const int tid = threadIdx.x;
    const int base = blockIdx.x * 64;

    vdl[tid] = vd[tid];
    if (tid < 64) { biasl[tid] = b_sw[tid] + bl_ww[tid]; wgl[tid] = Wg[tid]; }
    for (int i = tid; i < 1024; i += 256) {
        int r = i >> 4, c4 = i & 15;
        float4 v = *(const float4*)(x_wells + (size_t)(base + r) * 64 + 4 * c4);
        *(float4*)(&xw[r][4 * c4]) = v;
    }
    // weight column (Wl_ww+Wr_ww) for channel cch, coalesced global (L2-hot)
    const int cch = tid & 63;
    float w[64];
#pragma unroll
    for (int d = 0; d < 64; ++d) w[d] = Wl_ww[d * 64 + cch] + Wr_ww[d * 64 + cch];
    __syncthreads();

    // ---- GAT phase: 4 passes x 16 wells, 16 lanes/well ----
    const int p = tid & 15;
#pragma unroll 1
    for (int pass = 0; pass < 4; ++pass) {
        const int wl = pass * 16 + (tid >> 4);
        // al_d[w,h] via vd: 16-lane cooperative matvec + xor allreduce
        float h0 = 0, h1 = 0, h2 = 0, h3 = 0;
        {
            float4 xv = *(const float4*)(&xw[wl][4 * p]);
            const float* vp = &vdl[16 * p];
            h0 = xv.x * vp[0] + xv.y * vp[4] + xv.z * vp[8]  + xv.w * vp[12];
            h1 = xv.x * vp[1] + xv.y * vp[5] + xv.z * vp[9]  + xv.w * vp[13];
            h2 = xv.x * vp[2] + xv.y * vp[6] + xv.z * vp[10] + xv.w * vp[14];
            h3 = xv.x * vp[3] + xv.y * vp[7] + xv.z * vp[11] + xv.w * vp[15];
        }
#pragma unroll
        for (int off = 1; off < 16; off <<= 1) {
            h0 += __shfl_xor(h0, off, 64);
            h1 += __shfl_xor(h1, off, 64);
            h2 += __shfl_xor(h2, off, 64);
            h3 += __shfl_xor(h3, off, 64);
        }
        const int wglob = base + wl;
        const int r0 = rowptr[wglob], r1 = rowptr[wglob + 1];
        float den0 = 0, den1 = 0, den2 = 0, den3 = 0;
        float n0[4] = {0, 0, 0, 0}, n1[4] = {0, 0, 0, 0};
        float n2[4] = {0, 0, 0, 0}, n3[4] = {0, 0, 0, 0};
        for (int j = r0; j < r1; ++j) {
            int s = csr_src[j];
            float4 as = ((const float4*)al_s)[s];
            float e0 = __expf(lrelu02(as.x + h0));
            float e1 = __expf(lrelu02(as.y + h1));
            float e2 = __expf(lrelu02(as.z + h2));
            float e3 = __expf(lrelu02(as.w + h3));
            den0 += e0; den1 += e1; den2 += e2; den3 += e3;
            const unsigned short* xr = xs + (size_t)s * 256 + 4 * p;
            ushort4 u0 = *(const ushort4*)(xr);
            ushort4 u1 = *(const ushort4*)(xr + 64);
            ushort4 u2 = *(const ushort4*)(xr + 128);
            ushort4 u3 = *(const ushort4*)(xr + 192);
            n0[0] += e0 * bf2f(u0.x); n0[1] += e0 * bf2f(u0.y); n0[2] += e0 * bf2f(u0.z); n0[3] += e0 * bf2f(u0.w);
            n1[0] += e1 * bf2f(u1.x); n1[1] += e1 * bf2f(u1.y); n1[2] += e1 * bf2f(u1.z); n1[3] += e1 * bf2f(u1.w);
            n2[0] += e2 * bf2f(u2.x); n2[1] += e2 * bf2f(u2.y); n2[2] += e2 * bf2f(u2.z); n2[3] += e2 * bf2f(u2.w);
            n3[0] += e3 * bf2f(u3.x); n3[1] += e3 * bf2f(u3.y); n3[2] += e3 * bf2f(u3.z); n3[3] += e3 * bf2f(u3.w);
        }
        const int c0 = 4 * p;
        float t[4];
        if (r1 > r0) {
            float i0 = 0.25f / den0, i1 = 0.25f / den1, i2 = 0.25f / den2, i3 = 0.25f / den3;
#pragma unroll
            for (int i = 0; i < 4; ++i)
                t[i] = n0[i] * i0 + n1[i] * i1 + n2[i] * i2 + n3[i] * i3 + biasl[c0 + i];
        } else {
#pragma unroll
            for (int i = 0; i < 4; ++i) t[i] = biasl[c0 + i];
        }
        *(float4*)(&tl[wl][c0]) = *(float4*)t;
    }
    __syncthreads();

    // ---- dense phase: wave q -> wells [16q,16q+16), lane = channel ----
    const int wq = tid >> 6;
    const float bg0 = bg[0];
#pragma unroll 1
    for (int wi = 0; wi < 16; ++wi) {
        const int wl = wq * 16 + wi;
        float t = tl[wl][cch];
        const float4* xr = (const float4*)(&xw[wl][0]);
#pragma unroll
        for (int q = 0; q < 16; ++q) {
            float4 xv = xr[q];
            t += xv.x * w[4 * q] + xv.y * w[4 * q + 1] + xv.z * w[4 * q + 2] + xv.w * w[4 * q + 3];
        }
        float r = fmaxf(t, 0.f) * wgl[cch];
#pragma unroll
        for (int off = 1; off < 64; off <<= 1) r += __shfl_xor(r, off, 64);
        if (cch == 0) {
            float o = r + bg0;
            out[base + wl] = o > 0.f ? o : 0.01f * o;
        }
    }
}

// ---------------------------------------------------------------------------
// Fused SAGE gather(mean) + self-loop GAT + relu + Wsit head for sites.
// Tile = 64 sites/block; same two-phase structure; 128 weight VGPRs.
// ---------------------------------------------------------------------------
__global__ void __launch_bounds__(256)
k_sage_sites(const float* __restrict__ x_sites, const float* __restrict__ x_wells,
             const int* __restrict__ rowptr, const int* __restrict__ csr_src,
             const float* __restrict__ Wl_ws, const float* __restrict__ bl_ws,
             const float* __restrict__ Wr_ws, const float* __restrict__ W_ss,
             const float* __restrict__ b_ss, const float* __restrict__ Wsit,
             const float* __restrict__ bsit, float* __restrict__ out)
{
    __shared__ float xl[64][68];
    __shared__ float ml[64][68];
    __shared__ float biasl[64], wsl[64];
    const int tid = threadIdx.x;
    const int base = blockIdx.x * 64;

    if (tid < 64) { biasl[tid] = bl_ws[tid] + b_ss[tid]; wsl[tid] = Wsit[tid]; }
    for (int i = tid; i < 1024; i += 256) {
        int r = i >> 4, c4 = i & 15;
        int s = base + r;
        float4 v = {0.f, 0.f, 0.f, 0.f};
        if (s < NS_) v = *(const float4*)(x_sites + (size_t)s * 64 + 4 * c4);
        *(float4*)(&xl[r][4 * c4]) = v;
    }
    const int cch = tid & 63;
    float wa[64], wb[64];
#pragma unroll
    for (int d = 0; d < 64; ++d) {
        wa[d] = Wl_ws[d * 64 + cch];
        wb[d] = Wr_ws[d * 64 + cch] + 0.25f * (W_ss[d * 256 + cch] + W_ss[d * 256 + 64 + cch] +
                                               W_ss[d * 256 + 128 + cch] + W_ss[d * 256 + 192 + cch]);
    }

    // ---- gather phase: 4 passes x 16 sites, 16 lanes/site ----
    const int p = tid & 15;
#pragma unroll 1
    for (int pass = 0; pass < 4; ++pass) {
        const int sl = pass * 16 + (tid >> 4);
        const int s = base + sl;
        float4 acc = {0.f, 0.f, 0.f, 0.f};
        if (s < NS_) {
            const int r0 = rowptr[s], r1 = rowptr[s + 1];
            for (int j = r0; j < r1; ++j) {
                int wsrc = csr_src[j];
                float4 xv = ((const float4*)(x_wells + (size_t)wsrc * 64))[p];
                acc.x += xv.x; acc.y += xv.y; acc.z += xv.z; acc.w += xv.w;
            }
            if (r1 > r0) {
                float rc = 1.f / (float)(r1 - r0);
                acc.x *= rc; acc.y *= rc; acc.z *= rc; acc.w *= rc;
            }
        }
        *(float4*)(&ml[sl][4 * p]) = acc;
    }
    __syncthreads();

    // ---- dense phase: wave q -> sites [16q,16q+16), lane = channel ----
    const int wq = tid >> 6;
    const float bs0 = bsit[0];
#pragma unroll 1
    for (int si = 0; si < 16; ++si) {
        const int sl = wq * 16 + si;
        const int s = base + sl;
        float t = biasl[cch];
        const float4* xr = (const float4*)(&xl[sl][0]);
        const float4* mr = (const float4*)(&ml[sl][0]);
#pragma unroll
        for (int q = 0; q < 16; ++q) {
            float4 xv = xr[q];
            float4 mv = mr[q];
            t += mv.x * wa[4 * q] + mv.y * wa[4 * q + 1] + mv.z * wa[4 * q + 2] + mv.w * wa[4 * q + 3];
            t += xv.x * wb[4 * q] + xv.y * wb[4 * q + 1] + xv.z * wb[4 * q + 2] + xv.w * wb[4 * q + 3];
        }
        float r = fmaxf(t, 0.f) * wsl[cch];
#pragma unroll
        for (int off = 1; off < 64; off <<= 1) r += __shfl_xor(r, off, 64);
        if (cch == 0 && s < NS_) {
            float o = r + bs0;
            out[(size_t)NW_ + s] = o > 0.f ? o : 0.01f * o;
        }
    }
}

// ---------------------------------------------------------------------------
extern "C" void kernel_launch(void* const* d_in, const int* in_sizes, int n_in,
                              void* d_out, int out_size, void* d_ws, size_t ws_size,
                              hipStream_t stream)
{
    const float* x_sites    = (const float*)d_in[0];
    const float* x_wells    = (const float*)d_in[1];
    const int*   e_sw_src   = (const int*)d_in[2];
    const int*   e_sw_dst   = (const int*)d_in[3];
    const int*   e_ws_src   = (const int*)d_in[4];
    const int*   e_ws_dst   = (const int*)d_in[5];
    const float* W_sw       = (const float*)d_in[6];
    const float* att_src_sw = (const float*)d_in[7];
    const float* att_dst_sw = (const float*)d_in[8];
    const float* b_sw       = (const float*)d_in[9];
    const float* Wl_ws      = (const float*)d_in[10];
    const float* bl_ws      = (const float*)d_in[11];
    const float* Wr_ws      = (const float*)d_in[12];
    const float* W_ss       = (const float*)d_in[13];
    // d_in[14], d_in[15]: att_*_ss cancel (softmax over single self edge == 1)
    const float* b_ss       = (const float*)d_in[16];
    const float* Wl_ww      = (const float*)d_in[17];
    const float* bl_ww      = (const float*)d_in[18];
    const float* Wr_ww      = (const float*)d_in[19];
    const float* Wg         = (const float*)d_in[20];
    const float* bg         = (const float*)d_in[21];
    const float* Wsit       = (const float*)d_in[22];
    const float* bsit       = (const float*)d_in[23];
    float* out = (float*)d_out;

    // workspace layout
    unsigned short* xs = (unsigned short*)d_ws;            // NS*256 bf16
    float* al_s = (float*)(xs + (size_t)NS_ * 256);        // NS*4
    float* vd   = al_s + (size_t)NS_ * 4;                  // 256
    int* ip     = (int*)(vd + 256);
    int* h_sw   = ip;                                      // NW   (zeroed)
    int* h_ws   = h_sw + NW_;                              // NS   (zeroed, adjacent)
    int* rp_sw  = h_ws + NS_;                              // NW+4
    int* cur_sw = rp_sw + NW_ + 4;                         // NW
    int* csr_sw = cur_sw + NW_;                            // E
    int* bs_sw  = csr_sw + NE_;                            // 256
    int* rp_ws  = bs_sw + 256;                             // NS+4
    int* cur_ws = rp_ws + NS_ + 4;                         // NS
    int* csr_ws = cur_ws + NS_;                            // E
    int* bs_ws  = csr_ws + NE_;                            // 256

    hipMemsetAsync(h_sw, 0, (size_t)(NW_ + NS_) * sizeof(int), stream);

    const int egrid = (NE_ + 255) / 256;
    const int nb_sw = (NW_ + EPB - 1) / EPB;   // 196
    const int nb_ws = (NS_ + EPB - 1) / EPB;   // 49

    hipLaunchKernelGGL(k_hist2, dim3(egrid, 2), dim3(256), 0, stream,
                       e_sw_dst, h_sw, e_ws_dst, h_ws);
    hipLaunchKernelGGL(k_scan1, dim3(nb_sw), dim3(256), 0, stream, h_sw, NW_, bs_sw);
    hipLaunchKernelGGL(k_scan1, dim3(nb_ws), dim3(256), 0, stream, h_ws, NS_, bs_ws);
    hipLaunchKernelGGL(k_scan2, dim3(1), dim3(256), 0, stream, bs_sw, nb_sw);
    hipLaunchKernelGGL(k_scan2, dim3(1), dim3(256), 0, stream, bs_ws, nb_ws);
    hipLaunchKernelGGL(k_scan3, dim3(nb_sw), dim3(256), 0, stream, h_sw, NW_, bs_sw, rp_sw, cur_sw, NE_);
    hipLaunchKernelGGL(k_scan3, dim3(nb_ws), dim3(256), 0, stream, h_ws, NS_, bs_ws, rp_ws, cur_ws, NE_);
    hipLaunchKernelGGL(k_scatter2, dim3(egrid, 2), dim3(256), 0, stream,
                       e_sw_src, e_sw_dst, cur_sw, csr_sw,
                       e_ws_src, e_ws_dst, cur_ws, csr_ws);

    hipLaunchKernelGGL(k_vd, dim3(1), dim3(256), 0, stream, W_sw, att_dst_sw, vd);
    hipLaunchKernelGGL(k_sites_pre, dim3(NS_ / 32), dim3(256), 0, stream,
                       x_sites, W_sw, att_src_sw, xs, al_s);

    hipLaunchKernelGGL(k_gat_wells, dim3(NW_ / 64), dim3(256), 0, stream,
                       x_wells, vd, rp_sw, csr_sw, al_s, xs,
                       Wl_ww, Wr_ww, b_sw, bl_ww, Wg, bg, out);
    hipLaunchKernelGGL(k_sage_sites, dim3((NS_ + 63) / 64), dim3(256), 0, stream,
                       x_sites, x_wells, rp_ws, csr_ws,
                       Wl_ws, bl_ws, Wr_ws, W_ss, b_ss, Wsit, bsit, out);
}

// Round 4
// 735.375 us; speedup vs baseline: 1.3085x; 1.3085x over previous
//
#include <hip/hip_runtime.h>

#define NS_ 100000
#define NW_ 400000
#define NE_ 500000
#define EPB 2048   // elements per scan block

__device__ __forceinline__ float lrelu02(float x) { return x > 0.f ? x : 0.2f * x; }
__device__ __forceinline__ float bf2f(unsigned short u) {
    return __uint_as_float(((unsigned)u) << 16);
}
__device__ __forceinline__ float bf2f_lo(unsigned u) {
    return __uint_as_float(u << 16);
}
__device__ __forceinline__ float bf2f_hi(unsigned u) {
    return __uint_as_float(u & 0xFFFF0000u);
}
__device__ __forceinline__ unsigned short f2bf(float f) {
    unsigned u = __float_as_uint(f);
    u += 0x7FFFu + ((u >> 16) & 1u);           // round-to-nearest-even
    return (unsigned short)(u >> 16);
}

// ---------------------------------------------------------------------------
// xs(bf16) = x_sites @ W_sw ([NS,256]) and al_s[n,h] = xs[n,h,:]·att_src[h,:]
// ---------------------------------------------------------------------------
__global__ void __launch_bounds__(256)
k_sites_pre(const float* __restrict__ x_sites, const float* __restrict__ W_sw,
            const float* __restrict__ att_src, unsigned short* __restrict__ xs,
            float* __restrict__ al_s)
{
    __shared__ float xlds[32][68];
    const int tid = threadIdx.x;
    float w[64];
#pragma unroll
    for (int d = 0; d < 64; ++d) w[d] = W_sw[d * 256 + tid];
    const float att = att_src[tid];
    const int base = blockIdx.x * 32;
    for (int i = tid; i < 32 * 64; i += 256) {
        int s = i >> 6, d = i & 63;
        xlds[s][d] = x_sites[(size_t)(base + s) * 64 + d];
    }
    __syncthreads();
    const int head = tid >> 6, lane = tid & 63;
    for (int s = 0; s < 32; ++s) {
        const float4* xr = (const float4*)(&xlds[s][0]);
        float acc = 0.f;
#pragma unroll
        for (int d4 = 0; d4 < 16; ++d4) {
            float4 xv = xr[d4];
            acc += xv.x * w[4 * d4] + xv.y * w[4 * d4 + 1] + xv.z * w[4 * d4 + 2] + xv.w * w[4 * d4 + 3];
        }
        xs[(size_t)(base + s) * 256 + tid] = f2bf(acc);
        float p = acc * att;
#pragma unroll
        for (int off = 32; off > 0; off >>= 1) p += __shfl_down(p, off, 64);
        if (lane == 0) al_s[(size_t)(base + s) * 4 + head] = p;
    }
}

// vd[d*4+h] = sum_c W_sw[d, h*64+c] * att_dst[h,c]   (single block)
__global__ void __launch_bounds__(256)
k_vd(const float* __restrict__ W_sw, const float* __restrict__ att_dst,
     float* __restrict__ vd)
{
    const int tid = threadIdx.x;
    const int d = tid >> 2, h = tid & 3;
    const float4* wp = (const float4*)(W_sw + d * 256 + h * 64);
    const float4* ap = (const float4*)(att_dst + h * 64);
    float acc = 0.f;
#pragma unroll
    for (int c = 0; c < 16; ++c) {
        float4 wv = wp[c]; float4 av = ap[c];
        acc += wv.x * av.x + wv.y * av.y + wv.z * av.z + wv.w * av.w;
    }
    vd[d * 4 + h] = acc;
}

// ---------------------------------------------------------------------------
// CSR build: histogram -> 3-phase scan -> scatter (both relations via y-dim)
// ---------------------------------------------------------------------------
__global__ void __launch_bounds__(256)
k_hist2(const int* __restrict__ d1, int* __restrict__ h1,
        const int* __restrict__ d2, int* __restrict__ h2)
{
    int e = blockIdx.x * 256 + threadIdx.x;
    if (e >= NE_) return;
    if (blockIdx.y == 0) atomicAdd(&h1[d1[e]], 1);
    else                 atomicAdd(&h2[d2[e]], 1);
}

__global__ void __launch_bounds__(256)
k_scan1(const int* __restrict__ hist, int n, int* __restrict__ bsum)
{
    __shared__ int red[256];
    const int tid = threadIdx.x;
    int base = blockIdx.x * EPB + tid * 8;
    int s = 0;
#pragma unroll
    for (int i = 0; i < 8; ++i) { int idx = base + i; if (idx < n) s += hist[idx]; }
    red[tid] = s;
    __syncthreads();
    for (int off = 128; off > 0; off >>= 1) {
        if (tid < off) red[tid] += red[tid + off];
        __syncthreads();
    }
    if (tid == 0) bsum[blockIdx.x] = red[0];
}

__global__ void __launch_bounds__(256)
k_scan2(int* __restrict__ bsum, int nb)
{
    __shared__ int sh[256];
    const int tid = threadIdx.x;
    sh[tid] = (tid < nb) ? bsum[tid] : 0;
    __syncthreads();
    for (int off = 1; off < 256; off <<= 1) {
        int u = (tid >= off) ? sh[tid - off] : 0;
        __syncthreads();
        sh[tid] += u;
        __syncthreads();
    }
    if (tid < nb) bsum[tid] = (tid == 0) ? 0 : sh[tid - 1];
}

__global__ void __launch_bounds__(256)
k_scan3(const int* __restrict__ hist, int n, const int* __restrict__ bsum,
        int* __restrict__ rowptr, int* __restrict__ cursor, int total)
{
    __shared__ int tsum[256];
    const int tid = threadIdx.x;
    int base = blockIdx.x * EPB + tid * 8;
    int v[8]; int s = 0;
#pragma unroll
    for (int i = 0; i < 8; ++i) {
        int idx = base + i;
        v[i] = (idx < n) ? hist[idx] : 0;
        s += v[i];
    }
    tsum[tid] = s;
    __syncthreads();
    for (int off = 1; off < 256; off <<= 1) {
        int u = (tid >= off) ? tsum[tid - off] : 0;
        __syncthreads();
        tsum[tid] += u;
        __syncthreads();
    }
    int texcl = tsum[tid] - s;
    int run = bsum[blockIdx.x] + texcl;
#pragma unroll
    for (int i = 0; i < 8; ++i) {
        int idx = base + i;
        if (idx < n) { rowptr[idx] = run; cursor[idx] = run; run += v[i]; }
    }
    if (blockIdx.x == 0 && tid == 0) rowptr[n] = total;
}

__global__ void __launch_bounds__(256)
k_scatter2(const int* __restrict__ s1, const int* __restrict__ d1,
           int* __restrict__ c1, int* __restrict__ o1,
           const int* __restrict__ s2, const int* __restrict__ d2,
           int* __restrict__ c2, int* __restrict__ o2)
{
    int e = blockIdx.x * 256 + threadIdx.x;
    if (e >= NE_) return;
    if (blockIdx.y == 0) { int p = atomicAdd(&c1[d1[e]], 1); o1[p] = s1[e]; }
    else                 { int p = atomicAdd(&c2[d2[e]], 1); o2[p] = s2[e]; }
}

// ---------------------------------------------------------------------------
// GAT gather (latency-bound -> low VGPR, high occupancy).
// 16 wells/block, 16 lanes/well. Writes tg = msg + bias (bf16, [NW,64]).
// ---------------------------------------------------------------------------
__global__ void __launch_bounds__(256)
k_gat_gather(const float* __restrict__ x_wells, const float* __restrict__ vd,
             const int* __restrict__ rowptr, const int* __restrict__ csr_src,
             const float* __restrict__ al_s, const unsigned short* __restrict__ xs,
             const float* __restrict__ b_sw, const float* __restrict__ bl_ww,
             unsigned short* __restrict__ tg)
{
    __shared__ float vdl[256];
    __shared__ float biasl[64];
    const int tid = threadIdx.x;
    vdl[tid] = vd[tid];
    if (tid < 64) biasl[tid] = b_sw[tid] + bl_ww[tid];
    __syncthreads();
    const int wl = tid >> 4, p = tid & 15;
    const int w = blockIdx.x * 16 + wl;
    // al_d[w,h]: 16-lane cooperative matvec + xor allreduce
    float h0, h1, h2, h3;
    {
        float4 xv = *(const float4*)(x_wells + (size_t)w * 64 + 4 * p);
        const float* vp = &vdl[16 * p];
        h0 = xv.x * vp[0] + xv.y * vp[4] + xv.z * vp[8]  + xv.w * vp[12];
        h1 = xv.x * vp[1] + xv.y * vp[5] + xv.z * vp[9]  + xv.w * vp[13];
        h2 = xv.x * vp[2] + xv.y * vp[6] + xv.z * vp[10] + xv.w * vp[14];
        h3 = xv.x * vp[3] + xv.y * vp[7] + xv.z * vp[11] + xv.w * vp[15];
    }
#pragma unroll
    for (int off = 1; off < 16; off <<= 1) {
        h0 += __shfl_xor(h0, off, 64);
        h1 += __shfl_xor(h1, off, 64);
        h2 += __shfl_xor(h2, off, 64);
        h3 += __shfl_xor(h3, off, 64);
    }
    const int r0 = rowptr[w], r1 = rowptr[w + 1];
    float den0 = 0, den1 = 0, den2 = 0, den3 = 0;
    float n0[4] = {0, 0, 0, 0}, n1[4] = {0, 0, 0, 0};
    float n2[4] = {0, 0, 0, 0}, n3[4] = {0, 0, 0, 0};
    for (int j = r0; j < r1; ++j) {
        int s = csr_src[j];
        float4 as = ((const float4*)al_s)[s];
        float e0 = __expf(lrelu02(as.x + h0));
        float e1 = __expf(lrelu02(as.y + h1));
        float e2 = __expf(lrelu02(as.z + h2));
        float e3 = __expf(lrelu02(as.w + h3));
        den0 += e0; den1 += e1; den2 += e2; den3 += e3;
        const unsigned short* xr = xs + (size_t)s * 256 + 4 * p;
        ushort4 u0 = *(const ushort4*)(xr);
        ushort4 u1 = *(const ushort4*)(xr + 64);
        ushort4 u2 = *(const ushort4*)(xr + 128);
        ushort4 u3 = *(const ushort4*)(xr + 192);
        n0[0] += e0 * bf2f(u0.x); n0[1] += e0 * bf2f(u0.y); n0[2] += e0 * bf2f(u0.z); n0[3] += e0 * bf2f(u0.w);
        n1[0] += e1 * bf2f(u1.x); n1[1] += e1 * bf2f(u1.y); n1[2] += e1 * bf2f(u1.z); n1[3] += e1 * bf2f(u1.w);
        n2[0] += e2 * bf2f(u2.x); n2[1] += e2 * bf2f(u2.y); n2[2] += e2 * bf2f(u2.z); n2[3] += e2 * bf2f(u2.w);
        n3[0] += e3 * bf2f(u3.x); n3[1] += e3 * bf2f(u3.y); n3[2] += e3 * bf2f(u3.z); n3[3] += e3 * bf2f(u3.w);
    }
    const int c0 = 4 * p;
    float t[4];
    if (r1 > r0) {
        float i0 = 0.25f / den0, i1 = 0.25f / den1, i2 = 0.25f / den2, i3 = 0.25f / den3;
#pragma unroll
        for (int i = 0; i < 4; ++i)
            t[i] = n0[i] * i0 + n1[i] * i1 + n2[i] * i2 + n3[i] * i3 + biasl[c0 + i];
    } else {
#pragma unroll
        for (int i = 0; i < 4; ++i) t[i] = biasl[c0 + i];
    }
    ushort4 o;
    o.x = f2bf(t[0]); o.y = f2bf(t[1]); o.z = f2bf(t[2]); o.w = f2bf(t[3]);
    *(ushort4*)(tg + (size_t)w * 64 + c0) = o;
}

// ---------------------------------------------------------------------------
// Wells dense: out[w] = lrelu(relu(tg + x_wells@(Wl_ww+Wr_ww))·Wg + bg).
// lane = channel (W column in 64 VGPRs); x row via wave-uniform s_loads.
// ---------------------------------------------------------------------------
__global__ void __launch_bounds__(256)
k_wells_dense(const float* __restrict__ x_wells, const unsigned short* __restrict__ tg,
              const float* __restrict__ Wl_ww, const float* __restrict__ Wr_ww,
              const float* __restrict__ Wg, const float* __restrict__ bg,
              float* __restrict__ out)
{
    const int tid = threadIdx.x;
    const int c = tid & 63;
    const int wq = __builtin_amdgcn_readfirstlane(tid >> 6);   // wave-uniform
    const int base = blockIdx.x * 64;
    float w[64];
#pragma unroll
    for (int d = 0; d < 64; ++d) w[d] = Wl_ww[d * 64 + c] + Wr_ww[d * 64 + c];
    const float wgc = Wg[c];
    const float bg0 = bg[0];
#pragma unroll 1
    for (int wi = 0; wi < 16; ++wi) {
        const int well = base + wq * 16 + wi;                  // wave-uniform
        const float* xr = x_wells + (size_t)well * 64;         // uniform -> s_load
        float t = bf2f(tg[(size_t)well * 64 + c]);
#pragma unroll
        for (int q = 0; q < 16; ++q) {
            float4 xv = *((const float4*)xr + q);
            t += xv.x * w[4 * q] + xv.y * w[4 * q + 1] + xv.z * w[4 * q + 2] + xv.w * w[4 * q + 3];
        }
        float r = fmaxf(t, 0.f) * wgc;
#pragma unroll
        for (int off = 1; off < 64; off <<= 1) r += __shfl_xor(r, off, 64);
        if (c == 0) {
            float o = r + bg0;
            out[well] = o > 0.f ? o : 0.01f * o;
        }
    }
}

// ---------------------------------------------------------------------------
// SAGE gather: mn[s,:] = mean of x_wells over incoming edges (bf16).
// 16 sites/block, 16 lanes/site.
// ---------------------------------------------------------------------------
__global__ void __launch_bounds__(256)
k_sage_gather(const float* __restrict__ x_wells, const int* __restrict__ rowptr,
              const int* __restrict__ csr_src, unsigned short* __restrict__ mn)
{
    const int tid = threadIdx.x;
    const int sl = tid >> 4, p = tid & 15;
    const int s = blockIdx.x * 16 + sl;
    const int r0 = rowptr[s], r1 = rowptr[s + 1];
    float4 acc = {0.f, 0.f, 0.f, 0.f};
    for (int j = r0; j < r1; ++j) {
        int wsrc = csr_src[j];
        float4 xv = ((const float4*)(x_wells + (size_t)wsrc * 64))[p];
        acc.x += xv.x; acc.y += xv.y; acc.z += xv.z; acc.w += xv.w;
    }
    if (r1 > r0) {
        float rc = 1.f / (float)(r1 - r0);
        acc.x *= rc; acc.y *= rc; acc.z *= rc; acc.w *= rc;
    }
    ushort4 o;
    o.x = f2bf(acc.x); o.y = f2bf(acc.y); o.z = f2bf(acc.z); o.w = f2bf(acc.w);
    *(ushort4*)(mn + (size_t)s * 64 + 4 * p) = o;
}

// ---------------------------------------------------------------------------
// Sites dense: t = mn@Wl_ws + x@(Wr_ws + mean_h W_ss) + biases;
// out[NW+s] = lrelu(relu(t)·Wsit + bsit). lane = channel; 128 weight VGPRs.
// ---------------------------------------------------------------------------
__global__ void __launch_bounds__(256)
k_sites_dense(const float* __restrict__ x_sites, const unsigned short* __restrict__ mn,
              const float* __restrict__ Wl_ws, const float* __restrict__ bl_ws,
              const float* __restrict__ Wr_ws, const float* __restrict__ W_ss,
              const float* __restrict__ b_ss, const float* __restrict__ Wsit,
              const float* __restrict__ bsit, float* __restrict__ out)
{
    const int tid = threadIdx.x;
    const int c = tid & 63;
    const int wq = __builtin_amdgcn_readfirstlane(tid >> 6);
    const int base = blockIdx.x * 64;
    float wa[64], wb[64];
#pragma unroll
    for (int d = 0; d < 64; ++d) {
        wa[d] = Wl_ws[d * 64 + c];
        wb[d] = Wr_ws[d * 64 + c] + 0.25f * (W_ss[d * 256 + c] + W_ss[d * 256 + 64 + c] +
                                             W_ss[d * 256 + 128 + c] + W_ss[d * 256 + 192 + c]);
    }
    const float biasc = bl_ws[c] + b_ss[c];
    const float wsc = Wsit[c];
    const float bs0 = bsit[0];
#pragma unroll 1
    for (int si = 0; si < 16; ++si) {
        const int site = base + wq * 16 + si;                  // wave-uniform
        if (site >= NS_) continue;
        const float* xr = x_sites + (size_t)site * 64;         // uniform -> s_load
        const unsigned* mr = (const unsigned*)(mn + (size_t)site * 64);  // uniform
        float t = biasc;
#pragma unroll
        for (int q = 0; q < 16; ++q) {
            float4 xv = *((const float4*)xr + q);
            t += xv.x * wb[4 * q] + xv.y * wb[4 * q + 1] + xv.z * wb[4 * q + 2] + xv.w * wb[4 * q + 3];
        }
#pragma unroll
        for (int q = 0; q < 32; ++q) {
            unsigned u = mr[q];
            t += bf2f_lo(u) * wa[2 * q] + bf2f_hi(u) * wa[2 * q + 1];
        }
        float r = fmaxf(t, 0.f) * wsc;
#pragma unroll
        for (int off = 1; off < 64; off <<= 1) r += __shfl_xor(r, off, 64);
        if (c == 0) {
            float o = r + bs0;
            out[(size_t)NW_ + site] = o > 0.f ? o : 0.01f * o;
        }
    }
}

// ---------------------------------------------------------------------------
extern "C" void kernel_launch(void* const* d_in, const int* in_sizes, int n_in,
                              void* d_out, int out_size, void* d_ws, size_t ws_size,
                              hipStream_t stream)
{
    const float* x_sites    = (const float*)d_in[0];
    const float* x_wells    = (const float*)d_in[1];
    const int*   e_sw_src   = (const int*)d_in[2];
    const int*   e_sw_dst   = (const int*)d_in[3];
    const int*   e_ws_src   = (const int*)d_in[4];
    const int*   e_ws_dst   = (const int*)d_in[5];
    const float* W_sw       = (const float*)d_in[6];
    const float* att_src_sw = (const float*)d_in[7];
    const float* att_dst_sw = (const float*)d_in[8];
    const float* b_sw       = (const float*)d_in[9];
    const float* Wl_ws      = (const float*)d_in[10];
    const float* bl_ws      = (const float*)d_in[11];
    const float* Wr_ws      = (const float*)d_in[12];
    const float* W_ss       = (const float*)d_in[13];
    // d_in[14], d_in[15]: att_*_ss cancel (softmax over single self edge == 1)
    const float* b_ss       = (const float*)d_in[16];
    const float* Wl_ww      = (const float*)d_in[17];
    const float* bl_ww      = (const float*)d_in[18];
    const float* Wr_ww      = (const float*)d_in[19];
    const float* Wg         = (const float*)d_in[20];
    const float* bg         = (const float*)d_in[21];
    const float* Wsit       = (const float*)d_in[22];
    const float* bsit       = (const float*)d_in[23];
    float* out = (float*)d_out;

    // workspace layout
    unsigned short* xs = (unsigned short*)d_ws;            // NS*256 bf16
    unsigned short* tg = xs + (size_t)NS_ * 256;           // NW*64 bf16
    unsigned short* mn = tg + (size_t)NW_ * 64;            // NS*64 bf16
    float* al_s = (float*)(mn + (size_t)NS_ * 64);         // NS*4
    float* vd   = al_s + (size_t)NS_ * 4;                  // 256
    int* ip     = (int*)(vd + 256);
    int* h_sw   = ip;                                      // NW   (zeroed)
    int* h_ws   = h_sw + NW_;                              // NS   (zeroed, adjacent)
    int* rp_sw  = h_ws + NS_;                              // NW+4
    int* cur_sw = rp_sw + NW_ + 4;                         // NW
    int* csr_sw = cur_sw + NW_;                            // E
    int* bs_sw  = csr_sw + NE_;                            // 256
    int* rp_ws  = bs_sw + 256;                             // NS+4
    int* cur_ws = rp_ws + NS_ + 4;                         // NS
    int* csr_ws = cur_ws + NS_;                            // E
    int* bs_ws  = csr_ws + NE_;                            // 256

    hipMemsetAsync(h_sw, 0, (size_t)(NW_ + NS_) * sizeof(int), stream);

    const int egrid = (NE_ + 255) / 256;
    const int nb_sw = (NW_ + EPB - 1) / EPB;   // 196
    const int nb_ws = (NS_ + EPB - 1) / EPB;   // 49

    hipLaunchKernelGGL(k_hist2, dim3(egrid, 2), dim3(256), 0, stream,
                       e_sw_dst, h_sw, e_ws_dst, h_ws);
    hipLaunchKernelGGL(k_scan1, dim3(nb_sw), dim3(256), 0, stream, h_sw, NW_, bs_sw);
    hipLaunchKernelGGL(k_scan1, dim3(nb_ws), dim3(256), 0, stream, h_ws, NS_, bs_ws);
    hipLaunchKernelGGL(k_scan2, dim3(1), dim3(256), 0, stream, bs_sw, nb_sw);
    hipLaunchKernelGGL(k_scan2, dim3(1), dim3(256), 0, stream, bs_ws, nb_ws);
    hipLaunchKernelGGL(k_scan3, dim3(nb_sw), dim3(256), 0, stream, h_sw, NW_, bs_sw, rp_sw, cur_sw, NE_);
    hipLaunchKernelGGL(k_scan3, dim3(nb_ws), dim3(256), 0, stream, h_ws, NS_, bs_ws, rp_ws, cur_ws, NE_);
    hipLaunchKernelGGL(k_scatter2, dim3(egrid, 2), dim3(256), 0, stream,
                       e_sw_src, e_sw_dst, cur_sw, csr_sw,
                       e_ws_src, e_ws_dst, cur_ws, csr_ws);

    hipLaunchKernelGGL(k_vd, dim3(1), dim3(256), 0, stream, W_sw, att_dst_sw, vd);
    hipLaunchKernelGGL(k_sites_pre, dim3(NS_ / 32), dim3(256), 0, stream,
                       x_sites, W_sw, att_src_sw, xs, al_s);

    hipLaunchKernelGGL(k_gat_gather, dim3(NW_ / 16), dim3(256), 0, stream,
                       x_wells, vd, rp_sw, csr_sw, al_s, xs, b_sw, bl_ww, tg);
    hipLaunchKernelGGL(k_wells_dense, dim3(NW_ / 64), dim3(256), 0, stream,
                       x_wells, tg, Wl_ww, Wr_ww, Wg, bg, out);
    hipLaunchKernelGGL(k_sage_gather, dim3(NS_ / 16), dim3(256), 0, stream,
                       x_wells, rp_ws, csr_ws, mn);
    hipLaunchKernelGGL(k_sites_dense, dim3((NS_ + 63) / 64), dim3(256), 0, stream,
                       x_sites, mn, Wl_ws, bl_ws, Wr_ws, W_ss, b_ss, Wsit, bsit, out);
}

// Round 5
// 577.573 us; speedup vs baseline: 1.6661x; 1.2732x over previous
//
#include <hip/hip_runtime.h>

#define NS_ 100000
#define NW_ 400000
#define NE_ 500000
#define EPB 2048   // elements per scan block

typedef float f32x4_t __attribute__((ext_vector_type(4)));
typedef unsigned u32x4_t __attribute__((ext_vector_type(4)));

__device__ __forceinline__ float lrelu02(float x) { return x > 0.f ? x : 0.2f * x; }
__device__ __forceinline__ float bf2f(unsigned short u) {
    return __uint_as_float(((unsigned)u) << 16);
}
__device__ __forceinline__ unsigned short f2bf(float f) {
    unsigned u = __float_as_uint(f);
    u += 0x7FFFu + ((u >> 16) & 1u);           // round-to-nearest-even
    return (unsigned short)(u >> 16);
}
__device__ __forceinline__ unsigned pk(float lo, float hi) {
    return (unsigned)f2bf(lo) | ((unsigned)f2bf(hi) << 16);
}
// D = A*B + D, 16x16x32 bf16. a/b = 8 bf16 packed in 4 dwords (k ascending).
// A[m=lane&15][k=(lane>>4)*8+j]; B[k=(lane>>4)*8+j][n=lane&15];
// D: col=lane&15, row=(lane>>4)*4+reg.
__device__ __forceinline__ void mfma_bf16(f32x4_t& acc, u32x4_t a, u32x4_t b) {
    asm volatile("v_mfma_f32_16x16x32_bf16 %0, %1, %2, %0" : "+v"(acc) : "v"(a), "v"(b));
}

// ---------------------------------------------------------------------------
// xs(bf16) = x_sites @ W_sw ([NS,256]) and al_s[n,h] = xs[n,h,:]·att_src[h,:]
// ---------------------------------------------------------------------------
__global__ void __launch_bounds__(256)
k_sites_pre(const float* __restrict__ x_sites, const float* __restrict__ W_sw,
            const float* __restrict__ att_src, unsigned short* __restrict__ xs,
            float* __restrict__ al_s)
{
    __shared__ float xlds[32][68];
    const int tid = threadIdx.x;
    float w[64];
#pragma unroll
    for (int d = 0; d < 64; ++d) w[d] = W_sw[d * 256 + tid];
    const float att = att_src[tid];
    const int base = blockIdx.x * 32;
    for (int i = tid; i < 32 * 64; i += 256) {
        int s = i >> 6, d = i & 63;
        xlds[s][d] = x_sites[(size_t)(base + s) * 64 + d];
    }
    __syncthreads();
    const int head = tid >> 6, lane = tid & 63;
    for (int s = 0; s < 32; ++s) {
        const float4* xr = (const float4*)(&xlds[s][0]);
        float acc = 0.f;
#pragma unroll
        for (int d4 = 0; d4 < 16; ++d4) {
            float4 xv = xr[d4];
            acc += xv.x * w[4 * d4] + xv.y * w[4 * d4 + 1] + xv.z * w[4 * d4 + 2] + xv.w * w[4 * d4 + 3];
        }
        xs[(size_t)(base + s) * 256 + tid] = f2bf(acc);
        float p = acc * att;
#pragma unroll
        for (int off = 32; off > 0; off >>= 1) p += __shfl_down(p, off, 64);
        if (lane == 0) al_s[(size_t)(base + s) * 4 + head] = p;
    }
}

// vd[d*4+h] = sum_c W_sw[d, h*64+c] * att_dst[h,c]   (single block)
__global__ void __launch_bounds__(256)
k_vd(const float* __restrict__ W_sw, const float* __restrict__ att_dst,
     float* __restrict__ vd)
{
    const int tid = threadIdx.x;
    const int d = tid >> 2, h = tid & 3;
    const float4* wp = (const float4*)(W_sw + d * 256 + h * 64);
    const float4* ap = (const float4*)(att_dst + h * 64);
    float acc = 0.f;
#pragma unroll
    for (int c = 0; c < 16; ++c) {
        float4 wv = wp[c]; float4 av = ap[c];
        acc += wv.x * av.x + wv.y * av.y + wv.z * av.z + wv.w * av.w;
    }
    vd[d * 4 + h] = acc;
}

// ---------------------------------------------------------------------------
// Weight B-fragment prep (bf16, MFMA lane order).
// fw: 8 frags (kc*4+ct) for wells:  Wc = Wl_ww + Wr_ww          (K=64)
// fs: 16 frags: kc 0..1 -> Wa = Wl_ws (mn path, K 0..63);
//               kc 2..3 -> Wb = Wr_ws + mean_h W_ss (x path, K 64..127)
// ---------------------------------------------------------------------------
__global__ void __launch_bounds__(256)
k_wprep(const float* __restrict__ Wl_ww, const float* __restrict__ Wr_ww,
        const float* __restrict__ Wl_ws, const float* __restrict__ Wr_ws,
        const float* __restrict__ W_ss,
        u32x4_t* __restrict__ fw, u32x4_t* __restrict__ fs)
{
    const int tid = threadIdx.x;
    for (int idx = tid; idx < 512; idx += 256) {
        int f = idx >> 6, lane = idx & 63;
        int kc = f >> 2, ct = f & 3, q = lane >> 4, n = lane & 15;
        int c = ct * 16 + n;
        u32x4_t d;
#pragma unroll
        for (int i = 0; i < 4; ++i) {
            int k = kc * 32 + q * 8 + 2 * i;
            float lo = Wl_ww[k * 64 + c] + Wr_ww[k * 64 + c];
            float hi = Wl_ww[(k + 1) * 64 + c] + Wr_ww[(k + 1) * 64 + c];
            d[i] = pk(lo, hi);
        }
        fw[idx] = d;
    }
    for (int idx = tid; idx < 1024; idx += 256) {
        int f = idx >> 6, lane = idx & 63;
        int kc = f >> 2, ct = f & 3, q = lane >> 4, n = lane & 15;
        int c = ct * 16 + n;
        u32x4_t d;
#pragma unroll
        for (int i = 0; i < 4; ++i) {
            int k = kc * 32 + q * 8 + 2 * i;
            float lo, hi;
            if (k < 64) {
                lo = Wl_ws[k * 64 + c];
                hi = Wl_ws[(k + 1) * 64 + c];
            } else {
                int kk = k - 64;
                lo = Wr_ws[kk * 64 + c] + 0.25f * (W_ss[kk * 256 + c] + W_ss[kk * 256 + 64 + c] +
                                                   W_ss[kk * 256 + 128 + c] + W_ss[kk * 256 + 192 + c]);
                hi = Wr_ws[(kk + 1) * 64 + c] + 0.25f * (W_ss[(kk + 1) * 256 + c] + W_ss[(kk + 1) * 256 + 64 + c] +
                                                         W_ss[(kk + 1) * 256 + 128 + c] + W_ss[(kk + 1) * 256 + 192 + c]);
            }
            d[i] = pk(lo, hi);
        }
        fs[idx] = d;
    }
}

// ---------------------------------------------------------------------------
// CSR build: histogram -> 3-phase scan -> scatter (both relations via y-dim)
// ---------------------------------------------------------------------------
__global__ void __launch_bounds__(256)
k_hist2(const int* __restrict__ d1, int* __restrict__ h1,
        const int* __restrict__ d2, int* __restrict__ h2)
{
    int e = blockIdx.x * 256 + threadIdx.x;
    if (e >= NE_) return;
    if (blockIdx.y == 0) atomicAdd(&h1[d1[e]], 1);
    else                 atomicAdd(&h2[d2[e]], 1);
}

__global__ void __launch_bounds__(256)
k_scan1(const int* __restrict__ hist, int n, int* __restrict__ bsum)
{
    __shared__ int red[256];
    const int tid = threadIdx.x;
    int base = blockIdx.x * EPB + tid * 8;
    int s = 0;
#pragma unroll
    for (int i = 0; i < 8; ++i) { int idx = base + i; if (idx < n) s += hist[idx]; }
    red[tid] = s;
    __syncthreads();
    for (int off = 128; off > 0; off >>= 1) {
        if (tid < off) red[tid] += red[tid + off];
        __syncthreads();
    }
    if (tid == 0) bsum[blockIdx.x] = red[0];
}

__global__ void __launch_bounds__(256)
k_scan2(int* __restrict__ bsum, int nb)
{
    __shared__ int sh[256];
    const int tid = threadIdx.x;
    sh[tid] = (tid < nb) ? bsum[tid] : 0;
    __syncthreads();
    for (int off = 1; off < 256; off <<= 1) {
        int u = (tid >= off) ? sh[tid - off] : 0;
        __syncthreads();
        sh[tid] += u;
        __syncthreads();
    }
    if (tid < nb) bsum[tid] = (tid == 0) ? 0 : sh[tid - 1];
}

__global__ void __launch_bounds__(256)
k_scan3(const int* __restrict__ hist, int n, const int* __restrict__ bsum,
        int* __restrict__ rowptr, int* __restrict__ cursor, int total)
{
    __shared__ int tsum[256];
    const int tid = threadIdx.x;
    int base = blockIdx.x * EPB + tid * 8;
    int v[8]; int s = 0;
#pragma unroll
    for (int i = 0; i < 8; ++i) {
        int idx = base + i;
        v[i] = (idx < n) ? hist[idx] : 0;
        s += v[i];
    }
    tsum[tid] = s;
    __syncthreads();
    for (int off = 1; off < 256; off <<= 1) {
        int u = (tid >= off) ? tsum[tid - off] : 0;
        __syncthreads();
        tsum[tid] += u;
        __syncthreads();
    }
    int texcl = tsum[tid] - s;
    int run = bsum[blockIdx.x] + texcl;
#pragma unroll
    for (int i = 0; i < 8; ++i) {
        int idx = base + i;
        if (idx < n) { rowptr[idx] = run; cursor[idx] = run; run += v[i]; }
    }
    if (blockIdx.x == 0 && tid == 0) rowptr[n] = total;
}

__global__ void __launch_bounds__(256)
k_scatter2(const int* __restrict__ s1, const int* __restrict__ d1,
           int* __restrict__ c1, int* __restrict__ o1,
           const int* __restrict__ s2, const int* __restrict__ d2,
           int* __restrict__ c2, int* __restrict__ o2)
{
    int e = blockIdx.x * 256 + threadIdx.x;
    if (e >= NE_) return;
    if (blockIdx.y == 0) { int p = atomicAdd(&c1[d1[e]], 1); o1[p] = s1[e]; }
    else                 { int p = atomicAdd(&c2[d2[e]], 1); o2[p] = s2[e]; }
}

// ---------------------------------------------------------------------------
// GAT gather (latency-bound -> low VGPR, high occupancy).
// 16 wells/block, 16 lanes/well. Writes tg = msg + bias (bf16, [NW,64]).
// ---------------------------------------------------------------------------
__global__ void __launch_bounds__(256)
k_gat_gather(const float* __restrict__ x_wells, const float* __restrict__ vd,
             const int* __restrict__ rowptr, const int* __restrict__ csr_src,
             const float* __restrict__ al_s, const unsigned short* __restrict__ xs,
             const float* __restrict__ b_sw, const float* __restrict__ bl_ww,
             unsigned short* __restrict__ tg)
{
    __shared__ float vdl[256];
    __shared__ float biasl[64];
    const int tid = threadIdx.x;
    vdl[tid] = vd[tid];
    if (tid < 64) biasl[tid] = b_sw[tid] + bl_ww[tid];
    __syncthreads();
    const int wl = tid >> 4, p = tid & 15;
    const int w = blockIdx.x * 16 + wl;
    float h0, h1, h2, h3;
    {
        float4 xv = *(const float4*)(x_wells + (size_t)w * 64 + 4 * p);
        const float* vp = &vdl[16 * p];
        h0 = xv.x * vp[0] + xv.y * vp[4] + xv.z * vp[8]  + xv.w * vp[12];
        h1 = xv.x * vp[1] + xv.y * vp[5] + xv.z * vp[9]  + xv.w * vp[13];
        h2 = xv.x * vp[2] + xv.y * vp[6] + xv.z * vp[10] + xv.w * vp[14];
        h3 = xv.x * vp[3] + xv.y * vp[7] + xv.z * vp[11] + xv.w * vp[15];
    }
#pragma unroll
    for (int off = 1; off < 16; off <<= 1) {
        h0 += __shfl_xor(h0, off, 64);
        h1 += __shfl_xor(h1, off, 64);
        h2 += __shfl_xor(h2, off, 64);
        h3 += __shfl_xor(h3, off, 64);
    }
    const int r0 = rowptr[w], r1 = rowptr[w + 1];
    float den0 = 0, den1 = 0, den2 = 0, den3 = 0;
    float n0[4] = {0, 0, 0, 0}, n1[4] = {0, 0, 0, 0};
    float n2[4] = {0, 0, 0, 0}, n3[4] = {0, 0, 0, 0};
    for (int j = r0; j < r1; ++j) {
        int s = csr_src[j];
        float4 as = ((const float4*)al_s)[s];
        float e0 = __expf(lrelu02(as.x + h0));
        float e1 = __expf(lrelu02(as.y + h1));
        float e2 = __expf(lrelu02(as.z + h2));
        float e3 = __expf(lrelu02(as.w + h3));
        den0 += e0; den1 += e1; den2 += e2; den3 += e3;
        const unsigned short* xr = xs + (size_t)s * 256 + 4 * p;
        ushort4 u0 = *(const ushort4*)(xr);
        ushort4 u1 = *(const ushort4*)(xr + 64);
        ushort4 u2 = *(const ushort4*)(xr + 128);
        ushort4 u3 = *(const ushort4*)(xr + 192);
        n0[0] += e0 * bf2f(u0.x); n0[1] += e0 * bf2f(u0.y); n0[2] += e0 * bf2f(u0.z); n0[3] += e0 * bf2f(u0.w);
        n1[0] += e1 * bf2f(u1.x); n1[1] += e1 * bf2f(u1.y); n1[2] += e1 * bf2f(u1.z); n1[3] += e1 * bf2f(u1.w);
        n2[0] += e2 * bf2f(u2.x); n2[1] += e2 * bf2f(u2.y); n2[2] += e2 * bf2f(u2.z); n2[3] += e2 * bf2f(u2.w);
        n3[0] += e3 * bf2f(u3.x); n3[1] += e3 * bf2f(u3.y); n3[2] += e3 * bf2f(u3.z); n3[3] += e3 * bf2f(u3.w);
    }
    const int c0 = 4 * p;
    float t[4];
    if (r1 > r0) {
        float i0 = 0.25f / den0, i1 = 0.25f / den1, i2 = 0.25f / den2, i3 = 0.25f / den3;
#pragma unroll
        for (int i = 0; i < 4; ++i)
            t[i] = n0[i] * i0 + n1[i] * i1 + n2[i] * i2 + n3[i] * i3 + biasl[c0 + i];
    } else {
#pragma unroll
        for (int i = 0; i < 4; ++i) t[i] = biasl[c0 + i];
    }
    ushort4 o;
    o.x = f2bf(t[0]); o.y = f2bf(t[1]); o.z = f2bf(t[2]); o.w = f2bf(t[3]);
    *(ushort4*)(tg + (size_t)w * 64 + c0) = o;
}

// ---------------------------------------------------------------------------
// Wells dense via MFMA: t = tg + x_wells@(Wl_ww+Wr_ww); out = lrelu(relu(t)·Wg+bg)
// Block 256 = 4 waves; wave = 16 wells; 8 MFMAs (2 kchunks x 4 ctiles).
// ---------------------------------------------------------------------------
__global__ void __launch_bounds__(256)
k_wells_dense(const float* __restrict__ x_wells, const unsigned short* __restrict__ tg,
              const u32x4_t* __restrict__ fw, const float* __restrict__ Wg,
              const float* __restrict__ bg, float* __restrict__ out)
{
    const int tid = threadIdx.x;
    const int wave = __builtin_amdgcn_readfirstlane(tid >> 6);
    const int lane = tid & 63, q = lane >> 4, n = lane & 15;
    const int wbase = blockIdx.x * 64 + wave * 16;
    const float* xr = x_wells + (size_t)(wbase + n) * 64 + q * 8;
    float4 x0 = *(const float4*)(xr);
    float4 x1 = *(const float4*)(xr + 4);
    float4 x2 = *(const float4*)(xr + 32);
    float4 x3 = *(const float4*)(xr + 36);
    u32x4_t a0 = { pk(x0.x, x0.y), pk(x0.z, x0.w), pk(x1.x, x1.y), pk(x1.z, x1.w) };
    u32x4_t a1 = { pk(x2.x, x2.y), pk(x2.z, x2.w), pk(x3.x, x3.y), pk(x3.z, x3.w) };
    f32x4_t acc0 = {0, 0, 0, 0}, acc1 = {0, 0, 0, 0}, acc2 = {0, 0, 0, 0}, acc3 = {0, 0, 0, 0};
    asm volatile("s_nop 3" : "+v"(a0), "+v"(a1), "+v"(acc0), "+v"(acc1), "+v"(acc2), "+v"(acc3));
    mfma_bf16(acc0, a0, fw[0 * 64 + lane]);
    mfma_bf16(acc1, a0, fw[1 * 64 + lane]);
    mfma_bf16(acc2, a0, fw[2 * 64 + lane]);
    mfma_bf16(acc3, a0, fw[3 * 64 + lane]);
    mfma_bf16(acc0, a1, fw[4 * 64 + lane]);
    mfma_bf16(acc1, a1, fw[5 * 64 + lane]);
    mfma_bf16(acc2, a1, fw[6 * 64 + lane]);
    mfma_bf16(acc3, a1, fw[7 * 64 + lane]);
    asm volatile("s_nop 7\n\ts_nop 7" : "+v"(acc0), "+v"(acc1), "+v"(acc2), "+v"(acc3));
    const float wg0 = Wg[n], wg1 = Wg[16 + n], wg2 = Wg[32 + n], wg3 = Wg[48 + n];
    const float bg0 = bg[0];
    float pr[4];
#pragma unroll
    for (int reg = 0; reg < 4; ++reg) {
        const int w = wbase + q * 4 + reg;
        const unsigned short* tr = tg + (size_t)w * 64 + n;
        float t0 = acc0[reg] + bf2f(tr[0]);
        float t1 = acc1[reg] + bf2f(tr[16]);
        float t2 = acc2[reg] + bf2f(tr[32]);
        float t3 = acc3[reg] + bf2f(tr[48]);
        float p = fmaxf(t0, 0.f) * wg0 + fmaxf(t1, 0.f) * wg1 +
                  fmaxf(t2, 0.f) * wg2 + fmaxf(t3, 0.f) * wg3;
        p += __shfl_xor(p, 1, 64);
        p += __shfl_xor(p, 2, 64);
        p += __shfl_xor(p, 4, 64);
        p += __shfl_xor(p, 8, 64);
        pr[reg] = p + bg0;
    }
    if (n == 0) {
        float4 o;
        o.x = pr[0] > 0.f ? pr[0] : 0.01f * pr[0];
        o.y = pr[1] > 0.f ? pr[1] : 0.01f * pr[1];
        o.z = pr[2] > 0.f ? pr[2] : 0.01f * pr[2];
        o.w = pr[3] > 0.f ? pr[3] : 0.01f * pr[3];
        *(float4*)(out + wbase + q * 4) = o;
    }
}

// ---------------------------------------------------------------------------
// SAGE gather: mn[s,:] = mean of x_wells over incoming edges (bf16).
// ---------------------------------------------------------------------------
__global__ void __launch_bounds__(256)
k_sage_gather(const float* __restrict__ x_wells, const int* __restrict__ rowptr,
              const int* __restrict__ csr_src, unsigned short* __restrict__ mn)
{
    const int tid = threadIdx.x;
    const int sl = tid >> 4, p = tid & 15;
    const int s = blockIdx.x * 16 + sl;
    const int r0 = rowptr[s], r1 = rowptr[s + 1];
    float4 acc = {0.f, 0.f, 0.f, 0.f};
    for (int j = r0; j < r1; ++j) {
        int wsrc = csr_src[j];
        float4 xv = ((const float4*)(x_wells + (size_t)wsrc * 64))[p];
        acc.x += xv.x; acc.y += xv.y; acc.z += xv.z; acc.w += xv.w;
    }
    if (r1 > r0) {
        float rc = 1.f / (float)(r1 - r0);
        acc.x *= rc; acc.y *= rc; acc.z *= rc; acc.w *= rc;
    }
    ushort4 o;
    o.x = f2bf(acc.x); o.y = f2bf(acc.y); o.z = f2bf(acc.z); o.w = f2bf(acc.w);
    *(ushort4*)(mn + (size_t)s * 64 + 4 * p) = o;
}

// ---------------------------------------------------------------------------
// Sites dense via MFMA: t = mn@Wl_ws + x@(Wr_ws+mean_h W_ss) + bias (K=128);
// out[NW+s] = lrelu(relu(t)·Wsit + bsit). 16 MFMAs/wave.
// ---------------------------------------------------------------------------
__global__ void __launch_bounds__(256)
k_sites_dense(const float* __restrict__ x_sites, const unsigned short* __restrict__ mn,
              const u32x4_t* __restrict__ fs, const float* __restrict__ bl_ws,
              const float* __restrict__ b_ss, const float* __restrict__ Wsit,
              const float* __restrict__ bsit, float* __restrict__ out)
{
    const int tid = threadIdx.x;
    const int wave = __builtin_amdgcn_readfirstlane(tid >> 6);
    const int lane = tid & 63, q = lane >> 4, n = lane & 15;
    const int sbase = blockIdx.x * 64 + wave * 16;
    const int srow = min(sbase + n, NS_ - 1);
    // mn A-frags (already bf16, row-major -> direct packed load)
    u32x4_t am0 = *(const u32x4_t*)(mn + (size_t)srow * 64 + q * 8);
    u32x4_t am1 = *(const u32x4_t*)(mn + (size_t)srow * 64 + 32 + q * 8);
    // x A-frags (fp32 -> bf16)
    const float* xr = x_sites + (size_t)srow * 64 + q * 8;
    float4 x0 = *(const float4*)(xr);
    float4 x1 = *(const float4*)(xr + 4);
    float4 x2 = *(const float4*)(xr + 32);
    float4 x3 = *(const float4*)(xr + 36);
    u32x4_t ax0 = { pk(x0.x, x0.y), pk(x0.z, x0.w), pk(x1.x, x1.y), pk(x1.z, x1.w) };
    u32x4_t ax1 = { pk(x2.x, x2.y), pk(x2.z, x2.w), pk(x3.x, x3.y), pk(x3.z, x3.w) };
    f32x4_t acc0 = {0, 0, 0, 0}, acc1 = {0, 0, 0, 0}, acc2 = {0, 0, 0, 0}, acc3 = {0, 0, 0, 0};
    asm volatile("s_nop 3" : "+v"(ax0), "+v"(ax1), "+v"(acc0), "+v"(acc1), "+v"(acc2), "+v"(acc3));
    mfma_bf16(acc0, am0, fs[0 * 64 + lane]);
    mfma_bf16(acc1, am0, fs[1 * 64 + lane]);
    mfma_bf16(acc2, am0, fs[2 * 64 + lane]);
    mfma_bf16(acc3, am0, fs[3 * 64 + lane]);
    mfma_bf16(acc0, am1, fs[4 * 64 + lane]);
    mfma_bf16(acc1, am1, fs[5 * 64 + lane]);
    mfma_bf16(acc2, am1, fs[6 * 64 + lane]);
    mfma_bf16(acc3, am1, fs[7 * 64 + lane]);
    mfma_bf16(acc0, ax0, fs[8 * 64 + lane]);
    mfma_bf16(acc1, ax0, fs[9 * 64 + lane]);
    mfma_bf16(acc2, ax0, fs[10 * 64 + lane]);
    mfma_bf16(acc3, ax0, fs[11 * 64 + lane]);
    mfma_bf16(acc0, ax1, fs[12 * 64 + lane]);
    mfma_bf16(acc1, ax1, fs[13 * 64 + lane]);
    mfma_bf16(acc2, ax1, fs[14 * 64 + lane]);
    mfma_bf16(acc3, ax1, fs[15 * 64 + lane]);
    asm volatile("s_nop 7\n\ts_nop 7" : "+v"(acc0), "+v"(acc1), "+v"(acc2), "+v"(acc3));
    const float b0 = bl_ws[n] + b_ss[n];
    const float b1 = bl_ws[16 + n] + b_ss[16 + n];
    const float b2 = bl_ws[32 + n] + b_ss[32 + n];
    const float b3 = bl_ws[48 + n] + b_ss[48 + n];
    const float w0 = Wsit[n], w1 = Wsit[16 + n], w2 = Wsit[32 + n], w3 = Wsit[48 + n];
    const float bs0 = bsit[0];
    float pr[4];
#pragma unroll
    for (int reg = 0; reg < 4; ++reg) {
        float t0 = acc0[reg] + b0;
        float t1 = acc1[reg] + b1;
        float t2 = acc2[reg] + b2;
        float t3 = acc3[reg] + b3;
        float p = fmaxf(t0, 0.f) * w0 + fmaxf(t1, 0.f) * w1 +
                  fmaxf(t2, 0.f) * w2 + fmaxf(t3, 0.f) * w3;
        p += __shfl_xor(p, 1, 64);
        p += __shfl_xor(p, 2, 64);
        p += __shfl_xor(p, 4, 64);
        p += __shfl_xor(p, 8, 64);
        pr[reg] = p + bs0;
    }
    if (n == 0) {
        const int s4 = sbase + q * 4;
        if (s4 + 3 < NS_) {
            float4 o;
            o.x = pr[0] > 0.f ? pr[0] : 0.01f * pr[0];
            o.y = pr[1] > 0.f ? pr[1] : 0.01f * pr[1];
            o.z = pr[2] > 0.f ? pr[2] : 0.01f * pr[2];
            o.w = pr[3] > 0.f ? pr[3] : 0.01f * pr[3];
            *(float4*)(out + (size_t)NW_ + s4) = o;
        } else {
#pragma unroll
            for (int reg = 0; reg < 4; ++reg) {
                if (s4 + reg < NS_) {
                    float v = pr[reg];
                    out[(size_t)NW_ + s4 + reg] = v > 0.f ? v : 0.01f * v;
                }
            }
        }
    }
}

// ---------------------------------------------------------------------------
extern "C" void kernel_launch(void* const* d_in, const int* in_sizes, int n_in,
                              void* d_out, int out_size, void* d_ws, size_t ws_size,
                              hipStream_t stream)
{
    const float* x_sites    = (const float*)d_in[0];
    const float* x_wells    = (const float*)d_in[1];
    const int*   e_sw_src   = (const int*)d_in[2];
    const int*   e_sw_dst   = (const int*)d_in[3];
    const int*   e_ws_src   = (const int*)d_in[4];
    const int*   e_ws_dst   = (const int*)d_in[5];
    const float* W_sw       = (const float*)d_in[6];
    const float* att_src_sw = (const float*)d_in[7];
    const float* att_dst_sw = (const float*)d_in[8];
    const float* b_sw       = (const float*)d_in[9];
    const float* Wl_ws      = (const float*)d_in[10];
    const float* bl_ws      = (const float*)d_in[11];
    const float* Wr_ws      = (const float*)d_in[12];
    const float* W_ss       = (const float*)d_in[13];
    // d_in[14], d_in[15]: att_*_ss cancel (softmax over single self edge == 1)
    const float* b_ss       = (const float*)d_in[16];
    const float* Wl_ww      = (const float*)d_in[17];
    const float* bl_ww      = (const float*)d_in[18];
    const float* Wr_ww      = (const float*)d_in[19];
    const float* Wg         = (const float*)d_in[20];
    const float* bg         = (const float*)d_in[21];
    const float* Wsit       = (const float*)d_in[22];
    const float* bsit       = (const float*)d_in[23];
    float* out = (float*)d_out;

    // workspace layout
    unsigned short* xs = (unsigned short*)d_ws;            // NS*256 bf16
    unsigned short* tg = xs + (size_t)NS_ * 256;           // NW*64 bf16
    unsigned short* mn = tg + (size_t)NW_ * 64;            // NS*64 bf16
    float* al_s = (float*)(mn + (size_t)NS_ * 64);         // NS*4
    float* vd   = al_s + (size_t)NS_ * 4;                  // 256
    u32x4_t* fw = (u32x4_t*)(vd + 256);                    // 512  (8 KB)
    u32x4_t* fs = fw + 512;                                // 1024 (16 KB)
    int* ip     = (int*)(fs + 1024);
    int* h_sw   = ip;                                      // NW   (zeroed)
    int* h_ws   = h_sw + NW_;                              // NS   (zeroed, adjacent)
    int* rp_sw  = h_ws + NS_;                              // NW+4
    int* cur_sw = rp_sw + NW_ + 4;                         // NW
    int* csr_sw = cur_sw + NW_;                            // E
    int* bs_sw  = csr_sw + NE_;                            // 256
    int* rp_ws  = bs_sw + 256;                             // NS+4
    int* cur_ws = rp_ws + NS_ + 4;                         // NS
    int* csr_ws = cur_ws + NS_;                            // E
    int* bs_ws  = csr_ws + NE_;                            // 256

    hipMemsetAsync(h_sw, 0, (size_t)(NW_ + NS_) * sizeof(int), stream);

    const int egrid = (NE_ + 255) / 256;
    const int nb_sw = (NW_ + EPB - 1) / EPB;   // 196
    const int nb_ws = (NS_ + EPB - 1) / EPB;   // 49

    hipLaunchKernelGGL(k_hist2, dim3(egrid, 2), dim3(256), 0, stream,
                       e_sw_dst, h_sw, e_ws_dst, h_ws);
    hipLaunchKernelGGL(k_scan1, dim3(nb_sw), dim3(256), 0, stream, h_sw, NW_, bs_sw);
    hipLaunchKernelGGL(k_scan1, dim3(nb_ws), dim3(256), 0, stream, h_ws, NS_, bs_ws);
    hipLaunchKernelGGL(k_scan2, dim3(1), dim3(256), 0, stream, bs_sw, nb_sw);
    hipLaunchKernelGGL(k_scan2, dim3(1), dim3(256), 0, stream, bs_ws, nb_ws);
    hipLaunchKernelGGL(k_scan3, dim3(nb_sw), dim3(256), 0, stream, h_sw, NW_, bs_sw, rp_sw, cur_sw, NE_);
    hipLaunchKernelGGL(k_scan3, dim3(nb_ws), dim3(256), 0, stream, h_ws, NS_, bs_ws, rp_ws, cur_ws, NE_);
    hipLaunchKernelGGL(k_scatter2, dim3(egrid, 2), dim3(256), 0, stream,
                       e_sw_src, e_sw_dst, cur_sw, csr_sw,
                       e_ws_src, e_ws_dst, cur_ws, csr_ws);

    hipLaunchKernelGGL(k_vd, dim3(1), dim3(256), 0, stream, W_sw, att_dst_sw, vd);
    hipLaunchKernelGGL(k_wprep, dim3(1), dim3(256), 0, stream,
                       Wl_ww, Wr_ww, Wl_ws, Wr_ws, W_ss, fw, fs);
    hipLaunchKernelGGL(k_sites_pre, dim3(NS_ / 32), dim3(256), 0, stream,
                       x_sites, W_sw, att_src_sw, xs, al_s);

    hipLaunchKernelGGL(k_gat_gather, dim3(NW_ / 16), dim3(256), 0, stream,
                       x_wells, vd, rp_sw, csr_sw, al_s, xs, b_sw, bl_ww, tg);
    hipLaunchKernelGGL(k_wells_dense, dim3(NW_ / 64), dim3(256), 0, stream,
                       x_wells, tg, fw, Wg, bg, out);
    hipLaunchKernelGGL(k_sage_gather, dim3(NS_ / 16), dim3(256), 0, stream,
                       x_wells, rp_ws, csr_ws, mn);
    hipLaunchKernelGGL(k_sites_dense, dim3((NS_ + 63) / 64), dim3(256), 0, stream,
                       x_sites, mn, fs, bl_ws, b_ss, Wsit, bsit, out);
}

// Round 6
// 499.256 us; speedup vs baseline: 1.9274x; 1.1569x over previous
//
#include <hip/hip_runtime.h>

#define NS_ 100000
#define NW_ 400000
#define NE_ 500000
#define EPB 2048   // elements per scan block

typedef float f32x4_t __attribute__((ext_vector_type(4)));
typedef unsigned u32x4_t __attribute__((ext_vector_type(4)));

__device__ __forceinline__ float lrelu02(float x) { return x > 0.f ? x : 0.2f * x; }
__device__ __forceinline__ float bf2f(unsigned short u) {
    return __uint_as_float(((unsigned)u) << 16);
}
__device__ __forceinline__ unsigned short f2bf(float f) {
    unsigned u = __float_as_uint(f);
    u += 0x7FFFu + ((u >> 16) & 1u);           // round-to-nearest-even
    return (unsigned short)(u >> 16);
}
__device__ __forceinline__ unsigned pk(float lo, float hi) {
    return (unsigned)f2bf(lo) | ((unsigned)f2bf(hi) << 16);
}
// D = A*B + D, 16x16x32 bf16. a/b = 8 bf16 packed in 4 dwords (k ascending).
// A[m=lane&15][k=(lane>>4)*8+j]; B[k=(lane>>4)*8+j][n=lane&15];
// D: col=lane&15, row=(lane>>4)*4+reg.   (layout HW-verified in rounds 4/5)
__device__ __forceinline__ void mfma_bf16(f32x4_t& acc, u32x4_t a, u32x4_t b) {
    asm volatile("v_mfma_f32_16x16x32_bf16 %0, %1, %2, %0" : "+v"(acc) : "v"(a), "v"(b));
}

// ---------------------------------------------------------------------------
// Prep (single block): vd/vs attention vectors + all weight B-fragments.
// fw : 8 frags  : Wc = Wl_ww + Wr_ww                      (wells dense, K=64)
// fs : 16 frags : kc0-1 Wl_ws (mn), kc2-3 Wr_ws+mean W_ss (sites dense, K=128)
// fsp: 32 frags : W_sw [64,256] for the sites projection   (kc*16+ct)
// ---------------------------------------------------------------------------
__global__ void __launch_bounds__(256)
k_prep(const float* __restrict__ W_sw, const float* __restrict__ att_src,
       const float* __restrict__ att_dst,
       const float* __restrict__ Wl_ww, const float* __restrict__ Wr_ww,
       const float* __restrict__ Wl_ws, const float* __restrict__ Wr_ws,
       const float* __restrict__ W_ss,
       float* __restrict__ vd, float* __restrict__ vs,
       u32x4_t* __restrict__ fw, u32x4_t* __restrict__ fs,
       u32x4_t* __restrict__ fsp)
{
    const int tid = threadIdx.x;
    {   // vd (att_dst) and vs (att_src): v[d*4+h] = sum_c W_sw[d,h*64+c]*att[h,c]
        int d = tid >> 2, h = tid & 3;
        const float4* wp = (const float4*)(W_sw + d * 256 + h * 64);
        const float4* ad = (const float4*)(att_dst + h * 64);
        const float4* as = (const float4*)(att_src + h * 64);
        float accd = 0.f, accs = 0.f;
#pragma unroll
        for (int c = 0; c < 16; ++c) {
            float4 wv = wp[c]; float4 dv = ad[c]; float4 sv = as[c];
            accd += wv.x * dv.x + wv.y * dv.y + wv.z * dv.z + wv.w * dv.w;
            accs += wv.x * sv.x + wv.y * sv.y + wv.z * sv.z + wv.w * sv.w;
        }
        vd[d * 4 + h] = accd;
        vs[d * 4 + h] = accs;
    }
    for (int idx = tid; idx < 512; idx += 256) {
        int f = idx >> 6, lane = idx & 63;
        int kc = f >> 2, ct = f & 3, q = lane >> 4, n = lane & 15;
        int c = ct * 16 + n;
        u32x4_t d;
#pragma unroll
        for (int i = 0; i < 4; ++i) {
            int k = kc * 32 + q * 8 + 2 * i;
            d[i] = pk(Wl_ww[k * 64 + c] + Wr_ww[k * 64 + c],
                      Wl_ww[(k + 1) * 64 + c] + Wr_ww[(k + 1) * 64 + c]);
        }
        fw[idx] = d;
    }
    for (int idx = tid; idx < 1024; idx += 256) {
        int f = idx >> 6, lane = idx & 63;
        int kc = f >> 2, ct = f & 3, q = lane >> 4, n = lane & 15;
        int c = ct * 16 + n;
        u32x4_t d;
#pragma unroll
        for (int i = 0; i < 4; ++i) {
            int k = kc * 32 + q * 8 + 2 * i;
            float lo, hi;
            if (k < 64) {
                lo = Wl_ws[k * 64 + c];
                hi = Wl_ws[(k + 1) * 64 + c];
            } else {
                int kk = k - 64;
                lo = Wr_ws[kk * 64 + c] + 0.25f * (W_ss[kk * 256 + c] + W_ss[kk * 256 + 64 + c] +
                                                   W_ss[kk * 256 + 128 + c] + W_ss[kk * 256 + 192 + c]);
                hi = Wr_ws[(kk + 1) * 64 + c] + 0.25f * (W_ss[(kk + 1) * 256 + c] + W_ss[(kk + 1) * 256 + 64 + c] +
                                                         W_ss[(kk + 1) * 256 + 128 + c] + W_ss[(kk + 1) * 256 + 192 + c]);
            }
            d[i] = pk(lo, hi);
        }
        fs[idx] = d;
    }
    for (int idx = tid; idx < 2048; idx += 256) {
        int f = idx >> 6, lane = idx & 63;
        int kc = f >> 4, ct = f & 15, q = lane >> 4, n = lane & 15;
        int c = ct * 16 + n;
        u32x4_t d;
#pragma unroll
        for (int i = 0; i < 4; ++i) {
            int k = kc * 32 + q * 8 + 2 * i;
            d[i] = pk(W_sw[k * 256 + c], W_sw[(k + 1) * 256 + c]);
        }
        fsp[idx] = d;
    }
}

// ---------------------------------------------------------------------------
// Sites projection via MFMA: xs(bf16)[NS,256] = x_sites @ W_sw, plus fused
// al_s = x_sites @ vs. Wave = 16 sites, 32 MFMAs; LDS-staged coalesced store.
// ---------------------------------------------------------------------------
#define SP_PAD 264   // 256 + 8 ushorts row pad (bank rotation for b16 stores)
__global__ void __launch_bounds__(256)
k_sites_pre(const float* __restrict__ x_sites, const u32x4_t* __restrict__ fsp,
            const float* __restrict__ vs, unsigned short* __restrict__ xs,
            float* __restrict__ al_s)
{
    __shared__ unsigned short stg[4][16 * SP_PAD];
    __shared__ float vsl[256];
    const int tid = threadIdx.x;
    vsl[tid] = vs[tid];
    __syncthreads();
    const int wave = __builtin_amdgcn_readfirstlane(tid >> 6);
    const int lane = tid & 63, q = lane >> 4, n = lane & 15;
    const int sbase = blockIdx.x * 64 + wave * 16;
    const int srow = min(sbase + n, NS_ - 1);
    const float* xr = x_sites + (size_t)srow * 64 + q * 8;
    float4 x0 = *(const float4*)(xr);
    float4 x1 = *(const float4*)(xr + 4);
    float4 x2 = *(const float4*)(xr + 32);
    float4 x3 = *(const float4*)(xr + 36);
    u32x4_t am0 = { pk(x0.x, x0.y), pk(x0.z, x0.w), pk(x1.x, x1.y), pk(x1.z, x1.w) };
    u32x4_t am1 = { pk(x2.x, x2.y), pk(x2.z, x2.w), pk(x3.x, x3.y), pk(x3.z, x3.w) };
    // fused al_s partials over this lane's 16 k-values (fp32 x, exact path)
    float pa[4];
#pragma unroll
    for (int h = 0; h < 4; ++h) {
        const float* v0 = &vsl[(q * 8) * 4 + h];
        const float* v1 = &vsl[(32 + q * 8) * 4 + h];
        pa[h] = x0.x * v0[0]  + x0.y * v0[4]  + x0.z * v0[8]  + x0.w * v0[12]
              + x1.x * v0[16] + x1.y * v0[20] + x1.z * v0[24] + x1.w * v0[28]
              + x2.x * v1[0]  + x2.y * v1[4]  + x2.z * v1[8]  + x2.w * v1[12]
              + x3.x * v1[16] + x3.y * v1[20] + x3.z * v1[24] + x3.w * v1[28];
    }
#pragma unroll
    for (int h = 0; h < 4; ++h) {
        pa[h] += __shfl_xor(pa[h], 16, 64);
        pa[h] += __shfl_xor(pa[h], 32, 64);
    }
    if (q == 0 && sbase + n < NS_)
        *(float4*)(al_s + (size_t)(sbase + n) * 4) = make_float4(pa[0], pa[1], pa[2], pa[3]);

    f32x4_t acc[16];
#pragma unroll
    for (int ct = 0; ct < 16; ++ct) acc[ct] = (f32x4_t){0, 0, 0, 0};
    asm volatile("s_nop 3" : "+v"(am0), "+v"(am1));
#pragma unroll
    for (int ct = 0; ct < 16; ++ct) mfma_bf16(acc[ct], am0, fsp[ct * 64 + lane]);
#pragma unroll
    for (int ct = 0; ct < 16; ++ct) mfma_bf16(acc[ct], am1, fsp[(16 + ct) * 64 + lane]);
    asm volatile("s_nop 7\n\ts_nop 7" ::: "memory");
    // stage to LDS (row = local site, col = channel), then coalesced copy-out
    unsigned short* ss = &stg[wave][0];
#pragma unroll
    for (int ct = 0; ct < 16; ++ct)
#pragma unroll
        for (int reg = 0; reg < 4; ++reg)
            ss[(q * 4 + reg) * SP_PAD + ct * 16 + n] = f2bf(acc[ct][reg]);
    __builtin_amdgcn_s_waitcnt(0);   // drain lgkm before wave-local readback
#pragma unroll
    for (int i = 0; i < 8; ++i) {
        int g = i * 64 + lane;
        int r = g >> 5, c = g & 31;
        if (sbase + r < NS_) {
            u32x4_t v = *(const u32x4_t*)(ss + r * SP_PAD + c * 8);
            *(u32x4_t*)(xs + (size_t)(sbase + r) * 256 + c * 8) = v;
        }
    }
}

// ---------------------------------------------------------------------------
// CSR build: histogram -> 3-phase scan -> scatter (relations merged per launch)
// ---------------------------------------------------------------------------
__global__ void __launch_bounds__(256)
k_hist2(const int* __restrict__ d1, int* __restrict__ h1,
        const int* __restrict__ d2, int* __restrict__ h2)
{
    int e = blockIdx.x * 256 + threadIdx.x;
    if (e >= NE_) return;
    if (blockIdx.y == 0) atomicAdd(&h1[d1[e]], 1);
    else                 atomicAdd(&h2[d2[e]], 1);
}

__global__ void __launch_bounds__(256)
k_scan1_2(const int* __restrict__ h1, int n1, int* __restrict__ b1, int nb1,
          const int* __restrict__ h2, int n2, int* __restrict__ b2)
{
    __shared__ int red[256];
    const int tid = threadIdx.x;
    const int bx = blockIdx.x;
    const int* hist; int n; int* bsum; int blk;
    if (bx < nb1) { hist = h1; n = n1; bsum = b1; blk = bx; }
    else          { hist = h2; n = n2; bsum = b2; blk = bx - nb1; }
    int base = blk * EPB + tid * 8;
    int s = 0;
#pragma unroll
    for (int i = 0; i < 8; ++i) { int idx = base + i; if (idx < n) s += hist[idx]; }
    red[tid] = s;
    __syncthreads();
    for (int off = 128; off > 0; off >>= 1) {
        if (tid < off) red[tid] += red[tid + off];
        __syncthreads();
    }
    if (tid == 0) bsum[blk] = red[0];
}

__global__ void __launch_bounds__(256)
k_scan2_2(int* __restrict__ b1, int nb1, int* __restrict__ b2, int nb2)
{
    __shared__ int sh[256];
    const int tid = threadIdx.x;
    int* bsum = blockIdx.x == 0 ? b1 : b2;
    int nb = blockIdx.x == 0 ? nb1 : nb2;
    sh[tid] = (tid < nb) ? bsum[tid] : 0;
    __syncthreads();
    for (int off = 1; off < 256; off <<= 1) {
        int u = (tid >= off) ? sh[tid - off] : 0;
        __syncthreads();
        sh[tid] += u;
        __syncthreads();
    }
    if (tid < nb) bsum[tid] = (tid == 0) ? 0 : sh[tid - 1];
}

__global__ void __launch_bounds__(256)
k_scan3_2(const int* __restrict__ h1, int n1, const int* __restrict__ b1,
          int* __restrict__ rp1, int* __restrict__ cu1, int nb1,
          const int* __restrict__ h2, int n2, const int* __restrict__ b2,
          int* __restrict__ rp2, int* __restrict__ cu2)
{
    __shared__ int tsum[256];
    const int tid = threadIdx.x;
    const int bx = blockIdx.x;
    const int* hist; int n; const int* bsum; int* rowptr; int* cursor; int blk;
    if (bx < nb1) { hist = h1; n = n1; bsum = b1; rowptr = rp1; cursor = cu1; blk = bx; }
    else          { hist = h2; n = n2; bsum = b2; rowptr = rp2; cursor = cu2; blk = bx - nb1; }
    int base = blk * EPB + tid * 8;
    int v[8]; int s = 0;
#pragma unroll
    for (int i = 0; i < 8; ++i) {
        int idx = base + i;
        v[i] = (idx < n) ? hist[idx] : 0;
        s += v[i];
    }
    tsum[tid] = s;
    __syncthreads();
    for (int off = 1; off < 256; off <<= 1) {
        int u = (tid >= off) ? tsum[tid - off] : 0;
        __syncthreads();
        tsum[tid] += u;
        __syncthreads();
    }
    int texcl = tsum[tid] - s;
    int run = bsum[blk] + texcl;
#pragma unroll
    for (int i = 0; i < 8; ++i) {
        int idx = base + i;
        if (idx < n) { rowptr[idx] = run; cursor[idx] = run; run += v[i]; }
    }
    if (blk == 0 && tid == 0) rowptr[n] = NE_;
}

__global__ void __launch_bounds__(256)
k_scatter2(const int* __restrict__ s1, const int* __restrict__ d1,
           int* __restrict__ c1, int* __restrict__ o1,
           const int* __restrict__ s2, const int* __restrict__ d2,
           int* __restrict__ c2, int* __restrict__ o2)
{
    int e = blockIdx.x * 256 + threadIdx.x;
    if (e >= NE_) return;
    if (blockIdx.y == 0) { int p = atomicAdd(&c1[d1[e]], 1); o1[p] = s1[e]; }
    else                 { int p = atomicAdd(&c2[d2[e]], 1); o2[p] = s2[e]; }
}

// ---------------------------------------------------------------------------
// GAT gather (latency-bound -> low VGPR, high occupancy).
// 16 wells/block, 16 lanes/well. Writes tg = msg + bias (bf16, [NW,64]).
// ---------------------------------------------------------------------------
__global__ void __launch_bounds__(256)
k_gat_gather(const float* __restrict__ x_wells, const float* __restrict__ vd,
             const int* __restrict__ rowptr, const int* __restrict__ csr_src,
             const float* __restrict__ al_s, const unsigned short* __restrict__ xs,
             const float* __restrict__ b_sw, const float* __restrict__ bl_ww,
             unsigned short* __restrict__ tg)
{
    __shared__ float vdl[256];
    __shared__ float biasl[64];
    const int tid = threadIdx.x;
    vdl[tid] = vd[tid];
    if (tid < 64) biasl[tid] = b_sw[tid] + bl_ww[tid];
    __syncthreads();
    const int wl = tid >> 4, p = tid & 15;
    const int w = blockIdx.x * 16 + wl;
    float h0, h1, h2, h3;
    {
        float4 xv = *(const float4*)(x_wells + (size_t)w * 64 + 4 * p);
        const float* vp = &vdl[16 * p];
        h0 = xv.x * vp[0] + xv.y * vp[4] + xv.z * vp[8]  + xv.w * vp[12];
        h1 = xv.x * vp[1] + xv.y * vp[5] + xv.z * vp[9]  + xv.w * vp[13];
        h2 = xv.x * vp[2] + xv.y * vp[6] + xv.z * vp[10] + xv.w * vp[14];
        h3 = xv.x * vp[3] + xv.y * vp[7] + xv.z * vp[11] + xv.w * vp[15];
    }
#pragma unroll
    for (int off = 1; off < 16; off <<= 1) {
        h0 += __shfl_xor(h0, off, 64);
        h1 += __shfl_xor(h1, off, 64);
        h2 += __shfl_xor(h2, off, 64);
        h3 += __shfl_xor(h3, off, 64);
    }
    const int r0 = rowptr[w], r1 = rowptr[w + 1];
    float den0 = 0, den1 = 0, den2 = 0, den3 = 0;
    float n0[4] = {0, 0, 0, 0}, n1[4] = {0, 0, 0, 0};
    float n2[4] = {0, 0, 0, 0}, n3[4] = {0, 0, 0, 0};
    for (int j = r0; j < r1; ++j) {
        int s = csr_src[j];
        float4 as = ((const float4*)al_s)[s];
        float e0 = __expf(lrelu02(as.x + h0));
        float e1 = __expf(lrelu02(as.y + h1));
        float e2 = __expf(lrelu02(as.z + h2));
        float e3 = __expf(lrelu02(as.w + h3));
        den0 += e0; den1 += e1; den2 += e2; den3 += e3;
        const unsigned short* xr = xs + (size_t)s * 256 + 4 * p;
        ushort4 u0 = *(const ushort4*)(xr);
        ushort4 u1 = *(const ushort4*)(xr + 64);
        ushort4 u2 = *(const ushort4*)(xr + 128);
        ushort4 u3 = *(const ushort4*)(xr + 192);
        n0[0] += e0 * bf2f(u0.x); n0[1] += e0 * bf2f(u0.y); n0[2] += e0 * bf2f(u0.z); n0[3] += e0 * bf2f(u0.w);
        n1[0] += e1 * bf2f(u1.x); n1[1] += e1 * bf2f(u1.y); n1[2] += e1 * bf2f(u1.z); n1[3] += e1 * bf2f(u1.w);
        n2[0] += e2 * bf2f(u2.x); n2[1] += e2 * bf2f(u2.y); n2[2] += e2 * bf2f(u2.z); n2[3] += e2 * bf2f(u2.w);
        n3[0] += e3 * bf2f(u3.x); n3[1] += e3 * bf2f(u3.y); n3[2] += e3 * bf2f(u3.z); n3[3] += e3 * bf2f(u3.w);
    }
    const int c0 = 4 * p;
    float t[4];
    if (r1 > r0) {
        float i0 = 0.25f / den0, i1 = 0.25f / den1, i2 = 0.25f / den2, i3 = 0.25f / den3;
#pragma unroll
        for (int i = 0; i < 4; ++i)
            t[i] = n0[i] * i0 + n1[i] * i1 + n2[i] * i2 + n3[i] * i3 + biasl[c0 + i];
    } else {
#pragma unroll
        for (int i = 0; i < 4; ++i) t[i] = biasl[c0 + i];
    }
    ushort4 o;
    o.x = f2bf(t[0]); o.y = f2bf(t[1]); o.z = f2bf(t[2]); o.w = f2bf(t[3]);
    *(ushort4*)(tg + (size_t)w * 64 + c0) = o;
}

// ---------------------------------------------------------------------------
// Wells dense via MFMA: t = tg + x_wells@(Wl_ww+Wr_ww); out = lrelu(relu(t)·Wg+bg)
// ---------------------------------------------------------------------------
__global__ void __launch_bounds__(256)
k_wells_dense(const float* __restrict__ x_wells, const unsigned short* __restrict__ tg,
              const u32x4_t* __restrict__ fw, const float* __restrict__ Wg,
              const float* __restrict__ bg, float* __restrict__ out)
{
    const int tid = threadIdx.x;
    const int wave = __builtin_amdgcn_readfirstlane(tid >> 6);
    const int lane = tid & 63, q = lane >> 4, n = lane & 15;
    const int wbase = blockIdx.x * 64 + wave * 16;
    const float* xr = x_wells + (size_t)(wbase + n) * 64 + q * 8;
    float4 x0 = *(const float4*)(xr);
    float4 x1 = *(const float4*)(xr + 4);
    float4 x2 = *(const float4*)(xr + 32);
    float4 x3 = *(const float4*)(xr + 36);
    u32x4_t a0 = { pk(x0.x, x0.y), pk(x0.z, x0.w), pk(x1.x, x1.y), pk(x1.z, x1.w) };
    u32x4_t a1 = { pk(x2.x, x2.y), pk(x2.z, x2.w), pk(x3.x, x3.y), pk(x3.z, x3.w) };
    f32x4_t acc0 = {0, 0, 0, 0}, acc1 = {0, 0, 0, 0}, acc2 = {0, 0, 0, 0}, acc3 = {0, 0, 0, 0};
    asm volatile("s_nop 3" : "+v"(a0), "+v"(a1), "+v"(acc0), "+v"(acc1), "+v"(acc2), "+v"(acc3));
    mfma_bf16(acc0, a0, fw[0 * 64 + lane]);
    mfma_bf16(acc1, a0, fw[1 * 64 + lane]);
    mfma_bf16(acc2, a0, fw[2 * 64 + lane]);
    mfma_bf16(acc3, a0, fw[3 * 64 + lane]);
    mfma_bf16(acc0, a1, fw[4 * 64 + lane]);
    mfma_bf16(acc1, a1, fw[5 * 64 + lane]);
    mfma_bf16(acc2, a1, fw[6 * 64 + lane]);
    mfma_bf16(acc3, a1, fw[7 * 64 + lane]);
    asm volatile("s_nop 7\n\ts_nop 7" : "+v"(acc0), "+v"(acc1), "+v"(acc2), "+v"(acc3));
    const float wg0 = Wg[n], wg1 = Wg[16 + n], wg2 = Wg[32 + n], wg3 = Wg[48 + n];
    const float bg0 = bg[0];
    float pr[4];
#pragma unroll
    for (int reg = 0; reg < 4; ++reg) {
        const int w = wbase + q * 4 + reg;
        const unsigned short* tr = tg + (size_t)w * 64 + n;
        float t0 = acc0[reg] + bf2f(tr[0]);
        float t1 = acc1[reg] + bf2f(tr[16]);
        float t2 = acc2[reg] + bf2f(tr[32]);
        float t3 = acc3[reg] + bf2f(tr[48]);
        float p = fmaxf(t0, 0.f) * wg0 + fmaxf(t1, 0.f) * wg1 +
                  fmaxf(t2, 0.f) * wg2 + fmaxf(t3, 0.f) * wg3;
        p += __shfl_xor(p, 1, 64);
        p += __shfl_xor(p, 2, 64);
        p += __shfl_xor(p, 4, 64);
        p += __shfl_xor(p, 8, 64);
        pr[reg] = p + bg0;
    }
    if (n == 0) {
        float4 o;
        o.x = pr[0] > 0.f ? pr[0] : 0.01f * pr[0];
        o.y = pr[1] > 0.f ? pr[1] : 0.01f * pr[1];
        o.z = pr[2] > 0.f ? pr[2] : 0.01f * pr[2];
        o.w = pr[3] > 0.f ? pr[3] : 0.01f * pr[3];
        *(float4*)(out + wbase + q * 4) = o;
    }
}

// ---------------------------------------------------------------------------
// SAGE gather: mn[s,:] = mean of x_wells over incoming edges (bf16).
// ---------------------------------------------------------------------------
__global__ void __launch_bounds__(256)
k_sage_gather(const float* __restrict__ x_wells, const int* __restrict__ rowptr,
              const int* __restrict__ csr_src, unsigned short* __restrict__ mn)
{
    const int tid = threadIdx.x;
    const int sl = tid >> 4, p = tid & 15;
    const int s = blockIdx.x * 16 + sl;
    const int r0 = rowptr[s], r1 = rowptr[s + 1];
    float4 acc = {0.f, 0.f, 0.f, 0.f};
    for (int j = r0; j < r1; ++j) {
        int wsrc = csr_src[j];
        float4 xv = ((const float4*)(x_wells + (size_t)wsrc * 64))[p];
        acc.x += xv.x; acc.y += xv.y; acc.z += xv.z; acc.w += xv.w;
    }
    if (r1 > r0) {
        float rc = 1.f / (float)(r1 - r0);
        acc.x *= rc; acc.y *= rc; acc.z *= rc; acc.w *= rc;
    }
    ushort4 o;
    o.x = f2bf(acc.x); o.y = f2bf(acc.y); o.z = f2bf(acc.z); o.w = f2bf(acc.w);
    *(ushort4*)(mn + (size_t)s * 64 + 4 * p) = o;
}

// ---------------------------------------------------------------------------
// Sites dense via MFMA: t = mn@Wl_ws + x@(Wr_ws+mean_h W_ss) + bias (K=128);
// out[NW+s] = lrelu(relu(t)·Wsit + bsit). 16 MFMAs/wave.
// ---------------------------------------------------------------------------
__global__ void __launch_bounds__(256)
k_sites_dense(const float* __restrict__ x_sites, const unsigned short* __restrict__ mn,
              const u32x4_t* __restrict__ fs, const float* __restrict__ bl_ws,
              const float* __restrict__ b_ss, const float* __restrict__ Wsit,
              const float* __restrict__ bsit, float* __restrict__ out)
{
    const int tid = threadIdx.x;
    const int wave = __builtin_amdgcn_readfirstlane(tid >> 6);
    const int lane = tid & 63, q = lane >> 4, n = lane & 15;
    const int sbase = blockIdx.x * 64 + wave * 16;
    const int srow = min(sbase + n, NS_ - 1);
    u32x4_t am0 = *(const u32x4_t*)(mn + (size_t)srow * 64 + q * 8);
    u32x4_t am1 = *(const u32x4_t*)(mn + (size_t)srow * 64 + 32 + q * 8);
    const float* xr = x_sites + (size_t)srow * 64 + q * 8;
    float4 x0 = *(const float4*)(xr);
    float4 x1 = *(const float4*)(xr + 4);
    float4 x2 = *(const float4*)(xr + 32);
    float4 x3 = *(const float4*)(xr + 36);
    u32x4_t ax0 = { pk(x0.x, x0.y), pk(x0.z, x0.w), pk(x1.x, x1.y), pk(x1.z, x1.w) };
    u32x4_t ax1 = { pk(x2.x, x2.y), pk(x2.z, x2.w), pk(x3.x, x3.y), pk(x3.z, x3.w) };
    f32x4_t acc0 = {0, 0, 0, 0}, acc1 = {0, 0, 0, 0}, acc2 = {0, 0, 0, 0}, acc3 = {0, 0, 0, 0};
    asm volatile("s_nop 3" : "+v"(ax0), "+v"(ax1), "+v"(acc0), "+v"(acc1), "+v"(acc2), "+v"(acc3));
    mfma_bf16(acc0, am0, fs[0 * 64 + lane]);
    mfma_bf16(acc1, am0, fs[1 * 64 + lane]);
    mfma_bf16(acc2, am0, fs[2 * 64 + lane]);
    mfma_bf16(acc3, am0, fs[3 * 64 + lane]);
    mfma_bf16(acc0, am1, fs[4 * 64 + lane]);
    mfma_bf16(acc1, am1, fs[5 * 64 + lane]);
    mfma_bf16(acc2, am1, fs[6 * 64 + lane]);
    mfma_bf16(acc3, am1, fs[7 * 64 + lane]);
    mfma_bf16(acc0, ax0, fs[8 * 64 + lane]);
    mfma_bf16(acc1, ax0, fs[9 * 64 + lane]);
    mfma_bf16(acc2, ax0, fs[10 * 64 + lane]);
    mfma_bf16(acc3, ax0, fs[11 * 64 + lane]);
    mfma_bf16(acc0, ax1, fs[12 * 64 + lane]);
    mfma_bf16(acc1, ax1, fs[13 * 64 + lane]);
    mfma_bf16(acc2, ax1, fs[14 * 64 + lane]);
    mfma_bf16(acc3, ax1, fs[15 * 64 + lane]);
    asm volatile("s_nop 7\n\ts_nop 7" : "+v"(acc0), "+v"(acc1), "+v"(acc2), "+v"(acc3));
    const float b0 = bl_ws[n] + b_ss[n];
    const float b1 = bl_ws[16 + n] + b_ss[16 + n];
    const float b2 = bl_ws[32 + n] + b_ss[32 + n];
    const float b3 = bl_ws[48 + n] + b_ss[48 + n];
    const float w0 = Wsit[n], w1 = Wsit[16 + n], w2 = Wsit[32 + n], w3 = Wsit[48 + n];
    const float bs0 = bsit[0];
    float pr[4];
#pragma unroll
    for (int reg = 0; reg < 4; ++reg) {
        float t0 = acc0[reg] + b0;
        float t1 = acc1[reg] + b1;
        float t2 = acc2[reg] + b2;
        float t3 = acc3[reg] + b3;
        float p = fmaxf(t0, 0.f) * w0 + fmaxf(t1, 0.f) * w1 +
                  fmaxf(t2, 0.f) * w2 + fmaxf(t3, 0.f) * w3;
        p += __shfl_xor(p, 1, 64);
        p += __shfl_xor(p, 2, 64);
        p += __shfl_xor(p, 4, 64);
        p += __shfl_xor(p, 8, 64);
        pr[reg] = p + bs0;
    }
    if (n == 0) {
        const int s4 = sbase + q * 4;
        if (s4 + 3 < NS_) {
            float4 o;
            o.x = pr[0] > 0.f ? pr[0] : 0.01f * pr[0];
            o.y = pr[1] > 0.f ? pr[1] : 0.01f * pr[1];
            o.z = pr[2] > 0.f ? pr[2] : 0.01f * pr[2];
            o.w = pr[3] > 0.f ? pr[3] : 0.01f * pr[3];
            *(float4*)(out + (size_t)NW_ + s4) = o;
        } else {
#pragma unroll
            for (int reg = 0; reg < 4; ++reg) {
                if (s4 + reg < NS_) {
                    float v = pr[reg];
                    out[(size_t)NW_ + s4 + reg] = v > 0.f ? v : 0.01f * v;
                }
            }
        }
    }
}

// ---------------------------------------------------------------------------
extern "C" void kernel_launch(void* const* d_in, const int* in_sizes, int n_in,
                              void* d_out, int out_size, void* d_ws, size_t ws_size,
                              hipStream_t stream)
{
    const float* x_sites    = (const float*)d_in[0];
    const float* x_wells    = (const float*)d_in[1];
    const int*   e_sw_src   = (const int*)d_in[2];
    const int*   e_sw_dst   = (const int*)d_in[3];
    const int*   e_ws_src   = (const int*)d_in[4];
    const int*   e_ws_dst   = (const int*)d_in[5];
    const float* W_sw       = (const float*)d_in[6];
    const float* att_src_sw = (const float*)d_in[7];
    const float* att_dst_sw = (const float*)d_in[8];
    const float* b_sw       = (const float*)d_in[9];
    const float* Wl_ws      = (const float*)d_in[10];
    const float* bl_ws      = (const float*)d_in[11];
    const float* Wr_ws      = (const float*)d_in[12];
    const float* W_ss       = (const float*)d_in[13];
    // d_in[14], d_in[15]: att_*_ss cancel (softmax over single self edge == 1)
    const float* b_ss       = (const float*)d_in[16];
    const float* Wl_ww      = (const float*)d_in[17];
    const float* bl_ww      = (const float*)d_in[18];
    const float* Wr_ww      = (const float*)d_in[19];
    const float* Wg         = (const float*)d_in[20];
    const float* bg         = (const float*)d_in[21];
    const float* Wsit       = (const float*)d_in[22];
    const float* bsit       = (const float*)d_in[23];
    float* out = (float*)d_out;

    // workspace layout
    unsigned short* xs = (unsigned short*)d_ws;            // NS*256 bf16
    unsigned short* tg = xs + (size_t)NS_ * 256;           // NW*64 bf16
    unsigned short* mn = tg + (size_t)NW_ * 64;            // NS*64 bf16
    float* al_s = (float*)(mn + (size_t)NS_ * 64);         // NS*4
    float* vd   = al_s + (size_t)NS_ * 4;                  // 256
    float* vs   = vd + 256;                                // 256
    u32x4_t* fw = (u32x4_t*)(vs + 256);                    // 512  (8 KB)
    u32x4_t* fs = fw + 512;                                // 1024 (16 KB)
    u32x4_t* fsp= fs + 1024;                               // 2048 (32 KB)
    int* ip     = (int*)(fsp + 2048);
    int* h_sw   = ip;                                      // NW   (zeroed)
    int* h_ws   = h_sw + NW_;                              // NS   (zeroed, adjacent)
    int* rp_sw  = h_ws + NS_;                              // NW+4
    int* cur_sw = rp_sw + NW_ + 4;                         // NW
    int* csr_sw = cur_sw + NW_;                            // E
    int* bs_sw  = csr_sw + NE_;                            // 256
    int* rp_ws  = bs_sw + 256;                             // NS+4
    int* cur_ws = rp_ws + NS_ + 4;                         // NS
    int* csr_ws = cur_ws + NS_;                            // E
    int* bs_ws  = csr_ws + NE_;                            // 256

    hipMemsetAsync(h_sw, 0, (size_t)(NW_ + NS_) * sizeof(int), stream);

    const int egrid = (NE_ + 255) / 256;
    const int nb_sw = (NW_ + EPB - 1) / EPB;   // 196
    const int nb_ws = (NS_ + EPB - 1) / EPB;   // 49

    hipLaunchKernelGGL(k_hist2, dim3(egrid, 2), dim3(256), 0, stream,
                       e_sw_dst, h_sw, e_ws_dst, h_ws);
    hipLaunchKernelGGL(k_scan1_2, dim3(nb_sw + nb_ws), dim3(256), 0, stream,
                       h_sw, NW_, bs_sw, nb_sw, h_ws, NS_, bs_ws);
    hipLaunchKernelGGL(k_scan2_2, dim3(2), dim3(256), 0, stream,
                       bs_sw, nb_sw, bs_ws, nb_ws);
    hipLaunchKernelGGL(k_scan3_2, dim3(nb_sw + nb_ws), dim3(256), 0, stream,
                       h_sw, NW_, bs_sw, rp_sw, cur_sw, nb_sw,
                       h_ws, NS_, bs_ws, rp_ws, cur_ws);
    hipLaunchKernelGGL(k_scatter2, dim3(egrid, 2), dim3(256), 0, stream,
                       e_sw_src, e_sw_dst, cur_sw, csr_sw,
                       e_ws_src, e_ws_dst, cur_ws, csr_ws);

    hipLaunchKernelGGL(k_prep, dim3(1), dim3(256), 0, stream,
                       W_sw, att_src_sw, att_dst_sw, Wl_ww, Wr_ww, Wl_ws, Wr_ws, W_ss,
                       vd, vs, fw, fs, fsp);
    hipLaunchKernelGGL(k_sites_pre, dim3((NS_ + 63) / 64), dim3(256), 0, stream,
                       x_sites, fsp, vs, xs, al_s);

    hipLaunchKernelGGL(k_gat_gather, dim3(NW_ / 16), dim3(256), 0, stream,
                       x_wells, vd, rp_sw, csr_sw, al_s, xs, b_sw, bl_ww, tg);
    hipLaunchKernelGGL(k_wells_dense, dim3(NW_ / 64), dim3(256), 0, stream,
                       x_wells, tg, fw, Wg, bg, out);
    hipLaunchKernelGGL(k_sage_gather, dim3(NS_ / 16), dim3(256), 0, stream,
                       x_wells, rp_ws, csr_ws, mn);
    hipLaunchKernelGGL(k_sites_dense, dim3((NS_ + 63) / 64), dim3(256), 0, stream,
                       x_sites, mn, fs, bl_ws, b_ss, Wsit, bsit, out);
}